// Round 11
// baseline (379.143 us; speedup 1.0000x reference)
//
#include <hip/hip_runtime.h>
#include <math.h>

#define N_PTS 8192
#define BATCH 4
#define CH 128
#define KNN 20
#define CAP 112
#define STQ 114
#define POOL 256

// ======================================================================
// LAPACK ssyevd emulation for 3x3 symmetric (lower), SINGLE precision,
// matching numpy's float32 eigh path bit-for-bit where decisions matter.
// (verified passing — do not perturb numerics)
// ======================================================================

__device__ __forceinline__ float slapy2f(float x, float y) {
#pragma clang fp contract(off)
  float ax = fabsf(x), ay = fabsf(y);
  float w = fmaxf(ax, ay), z = fminf(ax, ay);
  if (z == 0.0f) return w;
  float t = z / w;
  return w * sqrtf(1.0f + t * t);
}

__device__ __forceinline__ void slartgf(float f, float g, float* cs, float* sn, float* r) {
#pragma clang fp contract(off)
  if (g == 0.0f) { *cs = 1.0f; *sn = 0.0f; *r = f; }
  else if (f == 0.0f) { *cs = 0.0f; *sn = copysignf(1.0f, g); *r = fabsf(g); }
  else {
    float f1 = fabsf(f);
    float d = sqrtf(f * f + g * g);
    *cs = f1 / d;
    *r = copysignf(d, f);
    *sn = g / (*r);
  }
}

__device__ void slaev2f(float a, float b, float c, float* rt1, float* rt2,
                        float* cs1, float* sn1) {
#pragma clang fp contract(off)
  float sm = a + c, df = a - c, adf = fabsf(df);
  float tb = b + b, ab = fabsf(tb);
  float acmx, acmn;
  if (fabsf(a) > fabsf(c)) { acmx = a; acmn = c; } else { acmx = c; acmn = a; }
  float rt;
  if (adf > ab)      { float q = ab / adf;  rt = adf * sqrtf(1.0f + q * q); }
  else if (adf < ab) { float q = adf / ab;  rt = ab * sqrtf(1.0f + q * q); }
  else               rt = ab * sqrtf(2.0f);
  int sgn1;
  if (sm < 0.0f)      { *rt1 = 0.5f * (sm - rt); sgn1 = -1; *rt2 = (acmx / *rt1) * acmn - (b / *rt1) * b; }
  else if (sm > 0.0f) { *rt1 = 0.5f * (sm + rt); sgn1 = 1;  *rt2 = (acmx / *rt1) * acmn - (b / *rt1) * b; }
  else                { *rt1 = 0.5f * rt; *rt2 = -0.5f * rt; sgn1 = 1; }
  float cs; int sgn2;
  if (df >= 0.0f) { cs = df + rt; sgn2 = 1; } else { cs = df - rt; sgn2 = -1; }
  float acs = fabsf(cs);
  if (acs > ab) {
    float ct = -tb / cs;
    *sn1 = 1.0f / sqrtf(1.0f + ct * ct);
    *cs1 = ct * (*sn1);
  } else {
    if (ab == 0.0f) { *cs1 = 1.0f; *sn1 = 0.0f; }
    else {
      float tn = -cs / tb;
      *cs1 = 1.0f / sqrtf(1.0f + tn * tn);
      *sn1 = tn * (*cs1);
    }
  }
  if (sgn1 == sgn2) { float tn = *cs1; *cs1 = -(*sn1); *sn1 = tn; }
}

__device__ void eigh3_smallest(float a00, float a10, float a20,
                               float a11, float a21, float a22, float evec[3]) {
#pragma clang fp contract(off)
  float d[3], e[2], tau = 0.0f, v2 = 0.0f;
  d[0] = a00;
  {
    float xnorm = sqrtf(a20 * a20);   // snrm2(1)
    if (xnorm == 0.0f) {
      tau = 0.0f; v2 = 0.0f;
      e[0] = a10; d[1] = a11; e[1] = a21; d[2] = a22;
    } else {
      float alpha = a10;
      float beta = -copysignf(slapy2f(alpha, xnorm), alpha);
      tau = (beta - alpha) / beta;
      float invs = 1.0f / (alpha - beta);
      v2 = a20 * invs;
      e[0] = beta;
      float y0 = tau * a11;
      float y1 = tau * a21;
      y0 = y0 + tau * (a21 * v2);
      y1 = y1 + (tau * v2) * a22;
      float dot = y0 + y1 * v2;
      float al = (-0.5f * tau) * dot;
      float w0 = y0 + al;
      float w1 = y1 + al * v2;
      a11 = (a11 - w0) - w0;
      a21 = (a21 - v2 * w0) - w1;
      a22 = (a22 - v2 * w1) - w1 * v2;
      d[1] = a11; e[1] = a21; d[2] = a22;
    }
  }

  float z[3][3] = {{1.0f,0.0f,0.0f},{0.0f,1.0f,0.0f},{0.0f,0.0f,1.0f}};
  const float eps = 5.9604644775390625e-08f;
  const float eps2 = 3.5527136788005009e-15f;
  const float safmin = 1.1754943508222875e-38f;
  int nmaxit = 90, jtot = 0;
  int l1 = 0;
  int l, m, lend, lsv, lendsv;
  float p, g, r, c, s, f, b_, rt1, rt2, tst;
  float wc[2], wsn[2];

outer_loop:
  if (l1 > 2) goto sorting;
  if (l1 > 0) e[l1 - 1] = 0.0f;
  {
    int mm;
    for (mm = l1; mm <= 1; ++mm) {
      tst = fabsf(e[mm]);
      if (tst == 0.0f) break;
      if (tst <= (sqrtf(fabsf(d[mm])) * sqrtf(fabsf(d[mm + 1]))) * eps) { e[mm] = 0.0f; break; }
    }
    m = (mm > 1) ? 2 : mm;
  }
  l = l1; lsv = l; lend = m; lendsv = lend; l1 = m + 1;
  if (lend == l) goto outer_loop;
  {
    float an = 0.0f;
    for (int i2 = l; i2 <= lend; ++i2) an = fmaxf(an, fabsf(d[i2]));
    for (int i2 = l; i2 < lend; ++i2) an = fmaxf(an, fabsf(e[i2]));
    if (an == 0.0f) goto outer_loop;
  }
  if (fabsf(d[lend]) < fabsf(d[l])) { lend = lsv; l = lendsv; }

  if (lend > l) {
ql40:
    if (l != lend) {
      for (m = l; m <= lend - 1; ++m) {
        tst = e[m] * e[m];
        if (tst <= (eps2 * fabsf(d[m])) * fabsf(d[m + 1]) + safmin) goto ql60;
      }
    }
    m = lend;
ql60:
    if (m < lend) e[m] = 0.0f;
    p = d[l];
    if (m == l) goto ql80;
    if (m == l + 1) {
      slaev2f(d[l], e[l], d[l + 1], &rt1, &rt2, &c, &s);
      for (int i2 = 0; i2 < 3; ++i2) {
        float temp = z[i2][l + 1];
        z[i2][l + 1] = c * temp - s * z[i2][l];
        z[i2][l]     = s * temp + c * z[i2][l];
      }
      d[l] = rt1; d[l + 1] = rt2; e[l] = 0.0f;
      l += 2;
      if (l <= lend) goto ql40;
      goto done140;
    }
    if (jtot == nmaxit) goto done140;
    jtot++;
    g = (d[l + 1] - p) / (2.0f * e[l]);
    r = slapy2f(g, 1.0f);
    g = d[m] - p + e[l] / (g + copysignf(r, g));
    s = 1.0f; c = 1.0f; p = 0.0f;
    for (int i2 = m - 1; i2 >= l; --i2) {
      f = s * e[i2]; b_ = c * e[i2];
      slartgf(g, f, &c, &s, &r);
      if (i2 != m - 1) e[i2 + 1] = r;
      g = d[i2 + 1] - p;
      r = (d[i2] - g) * s + 2.0f * c * b_;
      p = s * r;
      d[i2 + 1] = g + p;
      g = c * r - b_;
      wc[i2] = c; wsn[i2] = -s;
    }
    for (int j = m - 1; j >= l; --j) {
      float ct = wc[j], st = wsn[j];
      for (int i2 = 0; i2 < 3; ++i2) {
        float temp = z[i2][j + 1];
        z[i2][j + 1] = ct * temp - st * z[i2][j];
        z[i2][j]     = st * temp + ct * z[i2][j];
      }
    }
    d[l] -= p;
    e[l] = g;
    goto ql40;
ql80:
    d[l] = p;
    l += 1;
    if (l <= lend) goto ql40;
    goto done140;
  } else {
qr90:
    if (l != lend) {
      for (m = l; m >= lend + 1; --m) {
        tst = e[m - 1] * e[m - 1];
        if (tst <= (eps2 * fabsf(d[m])) * fabsf(d[m - 1]) + safmin) goto qr110;
      }
    }
    m = lend;
qr110:
    if (m > lend) e[m - 1] = 0.0f;
    p = d[l];
    if (m == l) goto qr130;
    if (m == l - 1) {
      slaev2f(d[l - 1], e[l - 1], d[l], &rt1, &rt2, &c, &s);
      for (int i2 = 0; i2 < 3; ++i2) {
        float temp = z[i2][l];
        z[i2][l]     = c * temp - s * z[i2][l - 1];
        z[i2][l - 1] = s * temp + c * z[i2][l - 1];
      }
      d[l - 1] = rt1; d[l] = rt2; e[l - 1] = 0.0f;
      l -= 2;
      if (l >= lend) goto qr90;
      goto done140;
    }
    if (jtot == nmaxit) goto done140;
    jtot++;
    g = (d[l - 1] - p) / (2.0f * e[l - 1]);
    r = slapy2f(g, 1.0f);
    g = d[m] - p + e[l - 1] / (g + copysignf(r, g));
    s = 1.0f; c = 1.0f; p = 0.0f;
    for (int i2 = m; i2 <= l - 1; ++i2) {
      f = s * e[i2]; b_ = c * e[i2];
      slartgf(g, f, &c, &s, &r);
      if (i2 != m) e[i2 - 1] = r;
      g = d[i2] - p;
      r = (d[i2 + 1] - g) * s + 2.0f * c * b_;
      p = s * r;
      d[i2] = g + p;
      g = c * r - b_;
      wc[i2] = c; wsn[i2] = s;
    }
    for (int j = m; j <= l - 1; ++j) {
      float ct = wc[j], st = wsn[j];
      for (int i2 = 0; i2 < 3; ++i2) {
        float temp = z[i2][j + 1];
        z[i2][j + 1] = ct * temp - st * z[i2][j];
        z[i2][j]     = st * temp + ct * z[i2][j];
      }
    }
    d[l] -= p;
    e[l - 1] = g;
    goto qr90;
qr130:
    d[l] = p;
    l -= 1;
    if (l >= lend) goto qr90;
    goto done140;
  }
done140:
  if (jtot < nmaxit) goto outer_loop;
sorting:
  for (int ii = 1; ii <= 2; ++ii) {
    int i_ = ii - 1, k = i_;
    p = d[i_];
    for (int j = ii; j <= 2; ++j) if (d[j] < p) { k = j; p = d[j]; }
    if (k != i_) {
      d[k] = d[i_]; d[i_] = p;
      for (int i2 = 0; i2 < 3; ++i2) { float tz = z[i2][i_]; z[i2][i_] = z[i2][k]; z[i2][k] = tz; }
    }
  }
  {
    float z10 = z[1][0], z20 = z[2][0];
    float sum = z10 + v2 * z20;
    evec[0] = z[0][0];
    evec[1] = z10 - tau * sum;
    evec[2] = z20 - tau * sum * v2;
  }
}

// ======================================================================
// Kernel 0: prep
// xyz4.w holds -0.5*|p|^2 (EXACT: power-of-2 scale). |p|^2 recoverable
// bit-exactly as -2*w => exact-distance formula downstream bit-identical.
// ======================================================================
__global__ __launch_bounds__(256) void prep_kernel(const float* __restrict__ xyz,
                                                   const float* __restrict__ w1,
                                                   const float* __restrict__ w2,
                                                   float4* __restrict__ xyz4,
                                                   float* __restrict__ w1t,
                                                   float* __restrict__ w2t,
                                                   float* __restrict__ stats) {
  int idx = blockIdx.x * 256 + threadIdx.x;
  if (idx < BATCH * N_PTS) {
    float x = xyz[idx * 3], y = xyz[idx * 3 + 1], zz = xyz[idx * 3 + 2];
    float sq = fmaf(zz, zz, fmaf(y, y, x * x));
    xyz4[idx] = make_float4(x, y, zz, -0.5f * sq);
  }
  if (idx < 132 * CH) {
    int cc = idx >> 7, o = idx & 127;
    w1t[idx] = (cc < 131) ? w1[o * 131 + cc] : 0.0f;
  }
  if (idx < CH * CH) {
    int cc = idx >> 7, o = idx & 127;
    w2t[idx] = w2[o * CH + cc];
  }
  if (idx < 256) stats[idx] = 0.0f;
}

// exact dist, bit-identical to original qdist (w fields hold -0.5*sq)
__device__ __forceinline__ float qdist2(const float4 qv, const float4 cv) {
  float dot = fmaf(qv.x, cv.x, fmaf(qv.y, cv.y, qv.z * cv.z));
  return fmaf(-2.0f, dot, (-2.0f * qv.w) + (-2.0f * cv.w));
}

__device__ __forceinline__ unsigned int distbits(float dist) {
  unsigned int du = __float_as_uint(dist);
  return (du & 0x80000000u) ? ~du : (du | 0x80000000u);  // monotone total order
}

// ======================================================================
// Kernel 1: exact 20-NN + FUSED NORMALS (round 11).
//  Scan structure = r9 (proven 181us). r10's fusion regressed because
//  the eigh tail ran on ONE wave: 64 divergent lanes serialize (cost ~
//  union of all lanes' QL paths) with only 2 waves/CU alive => ~48us
//  tail vs 38.5us saved. Fix: spread the 64 eighs over ALL 16 waves,
//  4 lanes each (wave w -> queries w*4..w*4+3 on lanes 0-3). Divergence
//  union shrinks 64->4 lanes/wave; 16 waves over 4 SIMDs hide latency.
//  Inputs bit-identical: ord order unchanged, query reloaded from xb,
//  eigh verbatim => absmax unchanged.
// ======================================================================
__global__ __launch_bounds__(1024, 8) void knn_normals_kernel(const float4* __restrict__ xyz4,
                                                              float4* __restrict__ nrm4) {
  __shared__ unsigned int lst_d[64 * STQ];      // 29184 B
  __shared__ unsigned short lst_i[64 * STQ];    // 14592 B
  __shared__ float2 bnd[16 * 64];               // 8192 B (top-2 per wave,lane)
  __shared__ unsigned long long pool[POOL];     // 2048 B
  __shared__ unsigned short ord[64 * KNN];      // 2560 B (sorted NN ids per query)
  __shared__ unsigned int qcnt[64];
  __shared__ unsigned int qflag[64];
  __shared__ unsigned int qover[64];
  __shared__ unsigned int pool_cnt;

  const int t = threadIdx.x;
  const int w = t >> 6, l = t & 63;
  const int batch = blockIdx.x >> 7;               // 128 blocks per batch
  const int q0 = (blockIdx.x & 127) << 6;          // 64 queries per block
  const float4* __restrict__ xb = xyz4 + batch * N_PTS;
  const float4 qv = xb[q0 + l];
  const float qw = -2.0f * qv.w;                   // exact |q|^2

  if (t < 64) { qcnt[t] = 0; qflag[t] = 0; qover[t] = 0; }
  if (t == 0) pool_cnt = 0;

  const int base = __builtin_amdgcn_readfirstlane(w * 512);

#define KF(cv) fmaf(qv.x, (cv).x, fmaf(qv.y, (cv).y, fmaf(qv.z, (cv).z, (cv).w)))

  // ---- P1: top-2-largest k over this wave's 512 pts (dual buffer) ----
  float a0 = -INFINITY, a1 = -INFINITY;
  {
    float4 pA0 = xb[base + 0], pA1 = xb[base + 1], pA2 = xb[base + 2], pA3 = xb[base + 3];
    float4 pB0 = xb[base + 4], pB1 = xb[base + 5], pB2 = xb[base + 6], pB3 = xb[base + 7];
#define TOP2(kk) { float tt = fminf(a0, kk); a0 = fmaxf(a0, kk); a1 = fmaxf(a1, tt); }
    for (int i = 0; i < 512; i += 8) {
      float k0 = KF(pA0); pA0 = xb[base + i + 8];
      float k1 = KF(pA1); pA1 = xb[base + i + 9];
      float k2 = KF(pA2); pA2 = xb[base + i + 10];
      float k3 = KF(pA3); pA3 = xb[base + i + 11];
      TOP2(k0) TOP2(k1) TOP2(k2) TOP2(k3)
      k0 = KF(pB0); pB0 = xb[base + i + 12];
      k1 = KF(pB1); pB1 = xb[base + i + 13];
      k2 = KF(pB2); pB2 = xb[base + i + 14];
      k3 = KF(pB3); pB3 = xb[base + i + 15];
      TOP2(k0) TOP2(k1) TOP2(k2) TOP2(k3)
    }
#undef TOP2
  }
  bnd[w * 64 + l] = make_float2(a0, a1);
  __syncthreads();

  // per-1024-group exact 3rd-largest of the 4 wave-pair candidates
  float kmin = INFINITY;
#pragma unroll
  for (int g = 0; g < 8; ++g) {
    float2 pa = bnd[(2 * g) * 64 + l];
    float2 pb = bnd[(2 * g + 1) * 64 + l];
    float third = fmaxf(fminf(pa.y, pb.x), fminf(pa.x, pb.y));
    kmin = fminf(kmin, third);
  }
  float Tq = fmaf(-2.0f, kmin, qw);
  Tq = Tq + (fabsf(Tq) * 2e-5f + 1e-3f);           // rounding slack (>>3e-5 worst case)
  const float thK = 0.5f * (qw - Tq) - 1e-3f;      // prefilter: k>=thK <=> dist_k<=Tq+2e-3

  // ---- P2: collect (dual buffer + 3-fma prefilter) ----
  {
    float4 pA0 = xb[base + 0], pA1 = xb[base + 1], pA2 = xb[base + 2], pA3 = xb[base + 3];
    float4 pB0 = xb[base + 4], pB1 = xb[base + 5], pB2 = xb[base + 6], pB3 = xb[base + 7];
#define COLLECT(cv, idx_) {                                                     \
      float k = KF(cv);                                                         \
      if (k >= thK) {                                                           \
        float dot = fmaf(qv.x, (cv).x, fmaf(qv.y, (cv).y, qv.z * (cv).z));      \
        float dist = fmaf(-2.0f, dot, qw + (-2.0f * (cv).w));                   \
        if (dist <= Tq) {                                                       \
          unsigned int db = distbits(dist);                                     \
          unsigned int pos = atomicAdd(&qcnt[l], 1u);                           \
          if (pos < CAP) {                                                      \
            lst_d[l * STQ + pos] = db;                                          \
            lst_i[l * STQ + pos] = (unsigned short)(idx_);                      \
          } else {                                                              \
            unsigned long long key = ((unsigned long long)db << 32)             \
                                   | ((unsigned int)l << 16) | (unsigned int)(idx_); \
            unsigned int pp = atomicAdd(&pool_cnt, 1u);                         \
            if (pp < POOL) { pool[pp] = key; qflag[l] = 1u; }                   \
            else qover[l] = 1u;                                                 \
          }                                                                     \
        }                                                                       \
      }                                                                         \
    }
    for (int i = 0; i < 512; i += 8) {
      float4 cA0 = pA0; pA0 = xb[base + i + 8];
      float4 cA1 = pA1; pA1 = xb[base + i + 9];
      float4 cA2 = pA2; pA2 = xb[base + i + 10];
      float4 cA3 = pA3; pA3 = xb[base + i + 11];
      COLLECT(cA0, base + i)     COLLECT(cA1, base + i + 1)
      COLLECT(cA2, base + i + 2) COLLECT(cA3, base + i + 3)
      float4 cB0 = pB0; pB0 = xb[base + i + 12];
      float4 cB1 = pB1; pB1 = xb[base + i + 13];
      float4 cB2 = pB2; pB2 = xb[base + i + 14];
      float4 cB3 = pB3; pB3 = xb[base + i + 15];
      COLLECT(cB0, base + i + 4) COLLECT(cB1, base + i + 5)
      COLLECT(cB2, base + i + 6) COLLECT(cB3, base + i + 7)
    }
#undef COLLECT
  }
#undef KF
  __syncthreads();

  // ---- P3: parallel top-20 (16 lanes per query, 64 queries) ----
  {
    const int qg = t >> 4, sub = t & 15;
    unsigned int n = qcnt[qg]; if (n > CAP) n = CAP;
    const unsigned int pcnt = (qflag[qg] && !qover[qg]) ? min(pool_cnt, (unsigned int)POOL) : 0u;

    if (qover[qg]) {
      if (sub == 0) {
        // exact serial fallback (astronomically rare)
        unsigned long long best[KNN];
#pragma unroll
        for (int j = 0; j < KNN; ++j) best[j] = ~0ULL;
        const float4 qv2 = xb[q0 + qg];
        for (int m = 0; m < N_PTS; ++m) {
          float dist = qdist2(qv2, xb[m]);
          unsigned long long p = ((unsigned long long)distbits(dist) << 32) | (unsigned int)m;
          if (p < best[KNN - 1]) {
            int j = KNN - 1;
            while (j > 0 && best[j - 1] > p) { best[j] = best[j - 1]; --j; }
            best[j] = p;
          }
        }
        for (int j = 0; j < KNN; ++j) ord[qg * KNN + j] = (unsigned short)(best[j] & 0xffffu);
      }
    } else {
      for (int r = 0; r < KNN; ++r) {
        unsigned long long best = ~0ULL; int bslot = 0;
        for (unsigned int s = sub; s < n; s += 16) {
          unsigned long long v = ((unsigned long long)lst_d[qg * STQ + s] << 16)
                               | (unsigned long long)lst_i[qg * STQ + s];
          if (v < best) { best = v; bslot = (int)s; }
        }
        for (unsigned int s = sub; s < pcnt; s += 16) {
          unsigned long long v = pool[s];
          if ((unsigned int)((v >> 16) & 0xffffu) == (unsigned int)qg) {
            unsigned long long pv = ((v >> 32) << 16) | (v & 0xffffULL);
            if (pv < best) { best = pv; bslot = 0x10000 | (int)s; }
          }
        }
#pragma unroll
        for (int mm = 1; mm < 16; mm <<= 1) {
          unsigned long long ob = __shfl_xor(best, mm, 64);
          int obs = __shfl_xor(bslot, mm, 64);
          if (ob < best) { best = ob; bslot = obs; }
        }
        int s = bslot & 0xffff;
        if ((s & 15) == sub) {
          if (bslot & 0x10000) pool[s] = ~0ULL;
          else lst_d[qg * STQ + s] = 0xFFFFFFFFu;   // sentinel > any finite distbits
        }
        if (sub == 0) ord[qg * KNN + r] = (unsigned short)(best & 0xffffu);
      }
    }
  }
  __syncthreads();

  // ---- Tail: covariance + eigh -> normals, SPREAD over all 16 waves ----
  // wave w handles queries w*4..w*4+3 on lanes 0-3: divergence union is
  // 4 lanes (not 64), and 16 waves across 4 SIMDs hide the QL latency.
  if (l < 4) {
    const int qi = w * 4 + l;
    const float4 qq = xb[q0 + qi];                 // bit-identical input
    float c00, c01, c02, c11, c12, c22;
    {
#pragma clang fp contract(off)
      c00 = 0.f; c01 = 0.f; c02 = 0.f; c11 = 0.f; c12 = 0.f; c22 = 0.f;
      for (int j = 0; j < KNN; ++j) {
        float4 pv = xb[ord[qi * KNN + j]];
        float dx = pv.x - qq.x, dy = pv.y - qq.y, dz = pv.z - qq.z;
        c00 = c00 + dx * dx; c01 = c01 + dx * dy; c02 = c02 + dx * dz;
        c11 = c11 + dy * dy; c12 = c12 + dy * dz; c22 = c22 + dz * dz;
      }
    }
    float ev[3];
    eigh3_smallest(c00, c01, c02, c11, c12, c22, ev);
    nrm4[batch * N_PTS + q0 + qi] = make_float4(ev[0], ev[1], ev[2], 0.0f);
  }
}

// ======================================================================
// Kernel 3: GEMM1 + BN stats
// ======================================================================
__global__ __launch_bounds__(256) void gemm1_stats_kernel(const float* __restrict__ x,
                                                          const float4* __restrict__ nrm4,
                                                          const float* __restrict__ w1t,
                                                          const float* __restrict__ b1,
                                                          float* __restrict__ sums,
                                                          float* __restrict__ sumsq) {
  __shared__ float lds[64 * 134];
  const int t = threadIdx.x;
  const int b = blockIdx.x >> 7;
  const int n0 = (blockIdx.x & 127) << 6;
  for (int idx = t; idx < CH * 64; idx += 256) {
    int cc = idx >> 6, nl = idx & 63;
    lds[nl * 134 + cc] = x[((size_t)(b * CH + cc)) * N_PTS + n0 + nl];
  }
  if (t < 64) {
    float4 nv = nrm4[b * N_PTS + n0 + t];
    lds[t * 134 + 128] = nv.x; lds[t * 134 + 129] = nv.y;
    lds[t * 134 + 130] = nv.z; lds[t * 134 + 131] = 0.0f;
  }
  __syncthreads();

  const int og = __builtin_amdgcn_readfirstlane(t >> 6);
  const int nl = t & 63;
  float acc[32];
#pragma unroll
  for (int k = 0; k < 32; ++k) acc[k] = b1[og * 32 + k];
  for (int c2 = 0; c2 < 66; ++c2) {
    float2 xv = *(const float2*)&lds[nl * 134 + 2 * c2];
    const float* wr0 = w1t + (2 * c2) * CH + og * 32;
    const float* wr1 = wr0 + CH;
#pragma unroll
    for (int k = 0; k < 32; ++k) acc[k] = fmaf(wr0[k], xv.x, acc[k]);
#pragma unroll
    for (int k = 0; k < 32; ++k) acc[k] = fmaf(wr1[k], xv.y, acc[k]);
  }
  __syncthreads();
#pragma unroll
  for (int k2 = 0; k2 < 16; ++k2)
    *(float2*)&lds[nl * 134 + og * 32 + 2 * k2] = make_float2(acc[2 * k2], acc[2 * k2 + 1]);
  __syncthreads();
  {
    int cc = t & 127, hf = t >> 7;
    float sm = 0.f, sq = 0.f;
    for (int rr = hf * 32; rr < hf * 32 + 32; ++rr) {
      float v = lds[rr * 134 + cc];
      sm += v; sq = fmaf(v, v, sq);
    }
    atomicAdd(&sums[cc], sm);
    atomicAdd(&sumsq[cc], sq);
  }
}

// ======================================================================
// Kernel 4: finalize BN scale/shift
// ======================================================================
__global__ void bn_finalize_kernel(const float* __restrict__ sums, const float* __restrict__ sumsq,
                                   const float* __restrict__ gamma, const float* __restrict__ beta,
                                   float* __restrict__ scale, float* __restrict__ shift) {
  int c = threadIdx.x;
  if (c < CH) {
    const double cnt = (double)(BATCH * N_PTS);
    double mean = (double)sums[c] / cnt;
    double var = (double)sumsq[c] / cnt - mean * mean;
    double inv = 1.0 / sqrt(var + 1e-5);
    double sc = (double)gamma[c] * inv;
    scale[c] = (float)sc;
    shift[c] = (float)((double)beta[c] - mean * sc);
  }
}

// ======================================================================
// Kernel 5: fused GEMM1 (recompute) + BN + ReLU + GEMM2 -> out
// ======================================================================
__global__ __launch_bounds__(256) void fused_out_kernel(const float* __restrict__ x,
                                                        const float4* __restrict__ nrm4,
                                                        const float* __restrict__ w1t,
                                                        const float* __restrict__ b1,
                                                        const float* __restrict__ w2t,
                                                        const float* __restrict__ b2,
                                                        const float* __restrict__ scale,
                                                        const float* __restrict__ shift,
                                                        float* __restrict__ out) {
  __shared__ float lds[64 * 134];
  const int t = threadIdx.x;
  const int b = blockIdx.x >> 7;
  const int n0 = (blockIdx.x & 127) << 6;
  for (int idx = t; idx < CH * 64; idx += 256) {
    int cc = idx >> 6, nl = idx & 63;
    lds[nl * 134 + cc] = x[((size_t)(b * CH + cc)) * N_PTS + n0 + nl];
  }
  if (t < 64) {
    float4 nv = nrm4[b * N_PTS + n0 + t];
    lds[t * 134 + 128] = nv.x; lds[t * 134 + 129] = nv.y;
    lds[t * 134 + 130] = nv.z; lds[t * 134 + 131] = 0.0f;
  }
  __syncthreads();

  const int og = __builtin_amdgcn_readfirstlane(t >> 6);
  const int nl = t & 63;
  float acc[32];
#pragma unroll
  for (int k = 0; k < 32; ++k) acc[k] = b1[og * 32 + k];
  for (int c2 = 0; c2 < 66; ++c2) {
    float2 xv = *(const float2*)&lds[nl * 134 + 2 * c2];
    const float* wr0 = w1t + (2 * c2) * CH + og * 32;
    const float* wr1 = wr0 + CH;
#pragma unroll
    for (int k = 0; k < 32; ++k) acc[k] = fmaf(wr0[k], xv.x, acc[k]);
#pragma unroll
    for (int k = 0; k < 32; ++k) acc[k] = fmaf(wr1[k], xv.y, acc[k]);
  }
#pragma unroll
  for (int k = 0; k < 32; ++k) {
    float sc = scale[og * 32 + k], sh = shift[og * 32 + k];
    acc[k] = fmaxf(fmaf(acc[k], sc, sh), 0.0f);
  }
  __syncthreads();
#pragma unroll
  for (int k2 = 0; k2 < 16; ++k2)
    *(float2*)&lds[nl * 134 + og * 32 + 2 * k2] = make_float2(acc[2 * k2], acc[2 * k2 + 1]);
  __syncthreads();

  float acc2[32];
#pragma unroll
  for (int k = 0; k < 32; ++k) acc2[k] = b2[og * 32 + k];
  for (int c2 = 0; c2 < 64; ++c2) {
    float2 hv = *(const float2*)&lds[nl * 134 + 2 * c2];
    const float* wr0 = w2t + (2 * c2) * CH + og * 32;
    const float* wr1 = wr0 + CH;
#pragma unroll
    for (int k = 0; k < 32; ++k) acc2[k] = fmaf(wr0[k], hv.x, acc2[k]);
#pragma unroll
    for (int k = 0; k < 32; ++k) acc2[k] = fmaf(wr1[k], hv.y, acc2[k]);
  }
#pragma unroll
  for (int k = 0; k < 32; ++k) {
    int o = og * 32 + k;
    out[((size_t)(b * CH + o)) * N_PTS + n0 + nl] = acc2[k];
  }
}

// ======================================================================
extern "C" void kernel_launch(void* const* d_in, const int* in_sizes, int n_in,
                              void* d_out, int out_size, void* d_ws, size_t ws_size,
                              hipStream_t stream) {
  const float* x     = (const float*)d_in[0];
  const float* xyz   = (const float*)d_in[1];
  const float* w1    = (const float*)d_in[2];
  const float* b1    = (const float*)d_in[3];
  const float* gamma = (const float*)d_in[4];
  const float* beta  = (const float*)d_in[5];
  const float* w2    = (const float*)d_in[6];
  const float* b2    = (const float*)d_in[7];
  float* out = (float*)d_out;

  float* W = (float*)d_ws;
  float4* xyz4 = (float4*)W;                         // 131072 floats
  float4* nrm4 = (float4*)(W + 131072);              // 131072 floats
  float* w1t   = W + 262144;
  float* w2t   = W + 279040;
  float* stats = W + 295424;
  float* scale = W + 295680;
  float* shift = W + 295808;

  prep_kernel<<<128, 256, 0, stream>>>(xyz, w1, w2, xyz4, w1t, w2t, stats);
  knn_normals_kernel<<<BATCH * N_PTS / 64, 1024, 0, stream>>>(xyz4, nrm4);
  gemm1_stats_kernel<<<BATCH * N_PTS / 64, 256, 0, stream>>>(x, nrm4, w1t, b1, stats, stats + 128);
  bn_finalize_kernel<<<1, 128, 0, stream>>>(stats, stats + 128, gamma, beta, scale, shift);
  fused_out_kernel<<<BATCH * N_PTS / 64, 256, 0, stream>>>(x, nrm4, w1t, b1, w2t, b2, scale, shift, out);
}

// Round 13
// 351.511 us; speedup vs baseline: 1.0786x; 1.0786x over previous
//
#include <hip/hip_runtime.h>
#include <math.h>

#define N_PTS 8192
#define BATCH 4
#define CH 128
#define KNN 20
#define CAP 112
#define STQ 114
#define POOL 256

// ======================================================================
// LAPACK ssyevd emulation for 3x3 symmetric (lower), SINGLE precision,
// matching numpy's float32 eigh path bit-for-bit where decisions matter.
// (verified passing — do not perturb numerics)
// ======================================================================

__device__ __forceinline__ float slapy2f(float x, float y) {
#pragma clang fp contract(off)
  float ax = fabsf(x), ay = fabsf(y);
  float w = fmaxf(ax, ay), z = fminf(ax, ay);
  if (z == 0.0f) return w;
  float t = z / w;
  return w * sqrtf(1.0f + t * t);
}

__device__ __forceinline__ void slartgf(float f, float g, float* cs, float* sn, float* r) {
#pragma clang fp contract(off)
  if (g == 0.0f) { *cs = 1.0f; *sn = 0.0f; *r = f; }
  else if (f == 0.0f) { *cs = 0.0f; *sn = copysignf(1.0f, g); *r = fabsf(g); }
  else {
    float f1 = fabsf(f);
    float d = sqrtf(f * f + g * g);
    *cs = f1 / d;
    *r = copysignf(d, f);
    *sn = g / (*r);
  }
}

__device__ void slaev2f(float a, float b, float c, float* rt1, float* rt2,
                        float* cs1, float* sn1) {
#pragma clang fp contract(off)
  float sm = a + c, df = a - c, adf = fabsf(df);
  float tb = b + b, ab = fabsf(tb);
  float acmx, acmn;
  if (fabsf(a) > fabsf(c)) { acmx = a; acmn = c; } else { acmx = c; acmn = a; }
  float rt;
  if (adf > ab)      { float q = ab / adf;  rt = adf * sqrtf(1.0f + q * q); }
  else if (adf < ab) { float q = adf / ab;  rt = ab * sqrtf(1.0f + q * q); }
  else               rt = ab * sqrtf(2.0f);
  int sgn1;
  if (sm < 0.0f)      { *rt1 = 0.5f * (sm - rt); sgn1 = -1; *rt2 = (acmx / *rt1) * acmn - (b / *rt1) * b; }
  else if (sm > 0.0f) { *rt1 = 0.5f * (sm + rt); sgn1 = 1;  *rt2 = (acmx / *rt1) * acmn - (b / *rt1) * b; }
  else                { *rt1 = 0.5f * rt; *rt2 = -0.5f * rt; sgn1 = 1; }
  float cs; int sgn2;
  if (df >= 0.0f) { cs = df + rt; sgn2 = 1; } else { cs = df - rt; sgn2 = -1; }
  float acs = fabsf(cs);
  if (acs > ab) {
    float ct = -tb / cs;
    *sn1 = 1.0f / sqrtf(1.0f + ct * ct);
    *cs1 = ct * (*sn1);
  } else {
    if (ab == 0.0f) { *cs1 = 1.0f; *sn1 = 0.0f; }
    else {
      float tn = -cs / tb;
      *cs1 = 1.0f / sqrtf(1.0f + tn * tn);
      *sn1 = tn * (*cs1);
    }
  }
  if (sgn1 == sgn2) { float tn = *cs1; *cs1 = -(*sn1); *sn1 = tn; }
}

__device__ void eigh3_smallest(float a00, float a10, float a20,
                               float a11, float a21, float a22, float evec[3]) {
#pragma clang fp contract(off)
  float d[3], e[2], tau = 0.0f, v2 = 0.0f;
  d[0] = a00;
  {
    float xnorm = sqrtf(a20 * a20);   // snrm2(1)
    if (xnorm == 0.0f) {
      tau = 0.0f; v2 = 0.0f;
      e[0] = a10; d[1] = a11; e[1] = a21; d[2] = a22;
    } else {
      float alpha = a10;
      float beta = -copysignf(slapy2f(alpha, xnorm), alpha);
      tau = (beta - alpha) / beta;
      float invs = 1.0f / (alpha - beta);
      v2 = a20 * invs;
      e[0] = beta;
      float y0 = tau * a11;
      float y1 = tau * a21;
      y0 = y0 + tau * (a21 * v2);
      y1 = y1 + (tau * v2) * a22;
      float dot = y0 + y1 * v2;
      float al = (-0.5f * tau) * dot;
      float w0 = y0 + al;
      float w1 = y1 + al * v2;
      a11 = (a11 - w0) - w0;
      a21 = (a21 - v2 * w0) - w1;
      a22 = (a22 - v2 * w1) - w1 * v2;
      d[1] = a11; e[1] = a21; d[2] = a22;
    }
  }

  float z[3][3] = {{1.0f,0.0f,0.0f},{0.0f,1.0f,0.0f},{0.0f,0.0f,1.0f}};
  const float eps = 5.9604644775390625e-08f;
  const float eps2 = 3.5527136788005009e-15f;
  const float safmin = 1.1754943508222875e-38f;
  int nmaxit = 90, jtot = 0;
  int l1 = 0;
  int l, m, lend, lsv, lendsv;
  float p, g, r, c, s, f, b_, rt1, rt2, tst;
  float wc[2], wsn[2];

outer_loop:
  if (l1 > 2) goto sorting;
  if (l1 > 0) e[l1 - 1] = 0.0f;
  {
    int mm;
    for (mm = l1; mm <= 1; ++mm) {
      tst = fabsf(e[mm]);
      if (tst == 0.0f) break;
      if (tst <= (sqrtf(fabsf(d[mm])) * sqrtf(fabsf(d[mm + 1]))) * eps) { e[mm] = 0.0f; break; }
    }
    m = (mm > 1) ? 2 : mm;
  }
  l = l1; lsv = l; lend = m; lendsv = lend; l1 = m + 1;
  if (lend == l) goto outer_loop;
  {
    float an = 0.0f;
    for (int i2 = l; i2 <= lend; ++i2) an = fmaxf(an, fabsf(d[i2]));
    for (int i2 = l; i2 < lend; ++i2) an = fmaxf(an, fabsf(e[i2]));
    if (an == 0.0f) goto outer_loop;
  }
  if (fabsf(d[lend]) < fabsf(d[l])) { lend = lsv; l = lendsv; }

  if (lend > l) {
ql40:
    if (l != lend) {
      for (m = l; m <= lend - 1; ++m) {
        tst = e[m] * e[m];
        if (tst <= (eps2 * fabsf(d[m])) * fabsf(d[m + 1]) + safmin) goto ql60;
      }
    }
    m = lend;
ql60:
    if (m < lend) e[m] = 0.0f;
    p = d[l];
    if (m == l) goto ql80;
    if (m == l + 1) {
      slaev2f(d[l], e[l], d[l + 1], &rt1, &rt2, &c, &s);
      for (int i2 = 0; i2 < 3; ++i2) {
        float temp = z[i2][l + 1];
        z[i2][l + 1] = c * temp - s * z[i2][l];
        z[i2][l]     = s * temp + c * z[i2][l];
      }
      d[l] = rt1; d[l + 1] = rt2; e[l] = 0.0f;
      l += 2;
      if (l <= lend) goto ql40;
      goto done140;
    }
    if (jtot == nmaxit) goto done140;
    jtot++;
    g = (d[l + 1] - p) / (2.0f * e[l]);
    r = slapy2f(g, 1.0f);
    g = d[m] - p + e[l] / (g + copysignf(r, g));
    s = 1.0f; c = 1.0f; p = 0.0f;
    for (int i2 = m - 1; i2 >= l; --i2) {
      f = s * e[i2]; b_ = c * e[i2];
      slartgf(g, f, &c, &s, &r);
      if (i2 != m - 1) e[i2 + 1] = r;
      g = d[i2 + 1] - p;
      r = (d[i2] - g) * s + 2.0f * c * b_;
      p = s * r;
      d[i2 + 1] = g + p;
      g = c * r - b_;
      wc[i2] = c; wsn[i2] = -s;
    }
    for (int j = m - 1; j >= l; --j) {
      float ct = wc[j], st = wsn[j];
      for (int i2 = 0; i2 < 3; ++i2) {
        float temp = z[i2][j + 1];
        z[i2][j + 1] = ct * temp - st * z[i2][j];
        z[i2][j]     = st * temp + ct * z[i2][j];
      }
    }
    d[l] -= p;
    e[l] = g;
    goto ql40;
ql80:
    d[l] = p;
    l += 1;
    if (l <= lend) goto ql40;
    goto done140;
  } else {
qr90:
    if (l != lend) {
      for (m = l; m >= lend + 1; --m) {
        tst = e[m - 1] * e[m - 1];
        if (tst <= (eps2 * fabsf(d[m])) * fabsf(d[m - 1]) + safmin) goto qr110;
      }
    }
    m = lend;
qr110:
    if (m > lend) e[m - 1] = 0.0f;
    p = d[l];
    if (m == l) goto qr130;
    if (m == l - 1) {
      slaev2f(d[l - 1], e[l - 1], d[l], &rt1, &rt2, &c, &s);
      for (int i2 = 0; i2 < 3; ++i2) {
        float temp = z[i2][l];
        z[i2][l]     = c * temp - s * z[i2][l - 1];
        z[i2][l - 1] = s * temp + c * z[i2][l - 1];
      }
      d[l - 1] = rt1; d[l] = rt2; e[l - 1] = 0.0f;
      l -= 2;
      if (l >= lend) goto qr90;
      goto done140;
    }
    if (jtot == nmaxit) goto done140;
    jtot++;
    g = (d[l - 1] - p) / (2.0f * e[l - 1]);
    r = slapy2f(g, 1.0f);
    g = d[m] - p + e[l - 1] / (g + copysignf(r, g));
    s = 1.0f; c = 1.0f; p = 0.0f;
    for (int i2 = m; i2 <= l - 1; ++i2) {
      f = s * e[i2]; b_ = c * e[i2];
      slartgf(g, f, &c, &s, &r);
      if (i2 != m) e[i2 - 1] = r;
      g = d[i2] - p;
      r = (d[i2 + 1] - g) * s + 2.0f * c * b_;
      p = s * r;
      d[i2] = g + p;
      g = c * r - b_;
      wc[i2] = c; wsn[i2] = s;
    }
    for (int j = m; j <= l - 1; ++j) {
      float ct = wc[j], st = wsn[j];
      for (int i2 = 0; i2 < 3; ++i2) {
        float temp = z[i2][j + 1];
        z[i2][j + 1] = ct * temp - st * z[i2][j];
        z[i2][j]     = st * temp + ct * z[i2][j];
      }
    }
    d[l] -= p;
    e[l - 1] = g;
    goto qr90;
qr130:
    d[l] = p;
    l -= 1;
    if (l >= lend) goto qr90;
    goto done140;
  }
done140:
  if (jtot < nmaxit) goto outer_loop;
sorting:
  for (int ii = 1; ii <= 2; ++ii) {
    int i_ = ii - 1, k = i_;
    p = d[i_];
    for (int j = ii; j <= 2; ++j) if (d[j] < p) { k = j; p = d[j]; }
    if (k != i_) {
      d[k] = d[i_]; d[i_] = p;
      for (int i2 = 0; i2 < 3; ++i2) { float tz = z[i2][i_]; z[i2][i_] = z[i2][k]; z[i2][k] = tz; }
    }
  }
  {
    float z10 = z[1][0], z20 = z[2][0];
    float sum = z10 + v2 * z20;
    evec[0] = z[0][0];
    evec[1] = z10 - tau * sum;
    evec[2] = z20 - tau * sum * v2;
  }
}

// ======================================================================
// Kernel 0: prep
// xyz4.w holds -0.5*|p|^2 (EXACT: power-of-2 scale). |p|^2 recoverable
// bit-exactly as -2*w => exact-distance formula downstream bit-identical.
// ======================================================================
__global__ __launch_bounds__(256) void prep_kernel(const float* __restrict__ xyz,
                                                   const float* __restrict__ w1,
                                                   const float* __restrict__ w2,
                                                   float4* __restrict__ xyz4,
                                                   float* __restrict__ w1t,
                                                   float* __restrict__ w2t,
                                                   float* __restrict__ stats) {
  int idx = blockIdx.x * 256 + threadIdx.x;
  if (idx < BATCH * N_PTS) {
    float x = xyz[idx * 3], y = xyz[idx * 3 + 1], zz = xyz[idx * 3 + 2];
    float sq = fmaf(zz, zz, fmaf(y, y, x * x));
    xyz4[idx] = make_float4(x, y, zz, -0.5f * sq);
  }
  if (idx < 132 * CH) {
    int cc = idx >> 7, o = idx & 127;
    w1t[idx] = (cc < 131) ? w1[o * 131 + cc] : 0.0f;
  }
  if (idx < CH * CH) {
    int cc = idx >> 7, o = idx & 127;
    w2t[idx] = w2[o * CH + cc];
  }
  if (idx < 256) stats[idx] = 0.0f;
}

// exact dist, bit-identical to original qdist (w fields hold -0.5*sq)
__device__ __forceinline__ float qdist2(const float4 qv, const float4 cv) {
  float dot = fmaf(qv.x, cv.x, fmaf(qv.y, cv.y, qv.z * cv.z));
  return fmaf(-2.0f, dot, (-2.0f * qv.w) + (-2.0f * cv.w));
}

__device__ __forceinline__ unsigned int distbits(float dist) {
  unsigned int du = __float_as_uint(dist);
  return (du & 0x80000000u) ? ~du : (du | 0x80000000u);  // monotone total order
}

// ======================================================================
// Kernel 1: exact 20-NN — r9 verbatim (proven 181us).
// ======================================================================
__global__ __launch_bounds__(1024, 8) void knn_select_kernel(const float4* __restrict__ xyz4,
                                                             unsigned short* __restrict__ nidx) {
  __shared__ unsigned int lst_d[64 * STQ];      // 29184 B
  __shared__ unsigned short lst_i[64 * STQ];    // 14592 B
  __shared__ float2 bnd[16 * 64];               // 8192 B (top-2 per wave,lane)
  __shared__ unsigned long long pool[POOL];     // 2048 B
  __shared__ unsigned int qcnt[64];
  __shared__ unsigned int qflag[64];
  __shared__ unsigned int qover[64];
  __shared__ unsigned int pool_cnt;

  const int t = threadIdx.x;
  const int w = t >> 6, l = t & 63;
  const int batch = blockIdx.x >> 7;               // 128 blocks per batch
  const int q0 = (blockIdx.x & 127) << 6;          // 64 queries per block
  const float4* __restrict__ xb = xyz4 + batch * N_PTS;
  const float4 qv = xb[q0 + l];
  const float qw = -2.0f * qv.w;                   // exact |q|^2

  if (t < 64) { qcnt[t] = 0; qflag[t] = 0; qover[t] = 0; }
  if (t == 0) pool_cnt = 0;

  const int base = __builtin_amdgcn_readfirstlane(w * 512);

#define KF(cv) fmaf(qv.x, (cv).x, fmaf(qv.y, (cv).y, fmaf(qv.z, (cv).z, (cv).w)))

  // ---- P1: top-2-largest k over this wave's 512 pts (dual buffer) ----
  float a0 = -INFINITY, a1 = -INFINITY;
  {
    float4 pA0 = xb[base + 0], pA1 = xb[base + 1], pA2 = xb[base + 2], pA3 = xb[base + 3];
    float4 pB0 = xb[base + 4], pB1 = xb[base + 5], pB2 = xb[base + 6], pB3 = xb[base + 7];
#define TOP2(kk) { float tt = fminf(a0, kk); a0 = fmaxf(a0, kk); a1 = fmaxf(a1, tt); }
    for (int i = 0; i < 512; i += 8) {
      float k0 = KF(pA0); pA0 = xb[base + i + 8];
      float k1 = KF(pA1); pA1 = xb[base + i + 9];
      float k2 = KF(pA2); pA2 = xb[base + i + 10];
      float k3 = KF(pA3); pA3 = xb[base + i + 11];
      TOP2(k0) TOP2(k1) TOP2(k2) TOP2(k3)
      k0 = KF(pB0); pB0 = xb[base + i + 12];
      k1 = KF(pB1); pB1 = xb[base + i + 13];
      k2 = KF(pB2); pB2 = xb[base + i + 14];
      k3 = KF(pB3); pB3 = xb[base + i + 15];
      TOP2(k0) TOP2(k1) TOP2(k2) TOP2(k3)
    }
#undef TOP2
  }
  bnd[w * 64 + l] = make_float2(a0, a1);
  __syncthreads();

  // per-1024-group exact 3rd-largest of the 4 wave-pair candidates
  float kmin = INFINITY;
#pragma unroll
  for (int g = 0; g < 8; ++g) {
    float2 pa = bnd[(2 * g) * 64 + l];
    float2 pb = bnd[(2 * g + 1) * 64 + l];
    float third = fmaxf(fminf(pa.y, pb.x), fminf(pa.x, pb.y));
    kmin = fminf(kmin, third);
  }
  float Tq = fmaf(-2.0f, kmin, qw);
  Tq = Tq + (fabsf(Tq) * 2e-5f + 1e-3f);           // rounding slack (>>3e-5 worst case)
  const float thK = 0.5f * (qw - Tq) - 1e-3f;      // prefilter: k>=thK <=> dist_k<=Tq+2e-3

  // ---- P2: collect (dual buffer + 3-fma prefilter) ----
  {
    float4 pA0 = xb[base + 0], pA1 = xb[base + 1], pA2 = xb[base + 2], pA3 = xb[base + 3];
    float4 pB0 = xb[base + 4], pB1 = xb[base + 5], pB2 = xb[base + 6], pB3 = xb[base + 7];
#define COLLECT(cv, idx_) {                                                     \
      float k = KF(cv);                                                         \
      if (k >= thK) {                                                           \
        float dot = fmaf(qv.x, (cv).x, fmaf(qv.y, (cv).y, qv.z * (cv).z));      \
        float dist = fmaf(-2.0f, dot, qw + (-2.0f * (cv).w));                   \
        if (dist <= Tq) {                                                       \
          unsigned int db = distbits(dist);                                     \
          unsigned int pos = atomicAdd(&qcnt[l], 1u);                           \
          if (pos < CAP) {                                                      \
            lst_d[l * STQ + pos] = db;                                          \
            lst_i[l * STQ + pos] = (unsigned short)(idx_);                      \
          } else {                                                              \
            unsigned long long key = ((unsigned long long)db << 32)             \
                                   | ((unsigned int)l << 16) | (unsigned int)(idx_); \
            unsigned int pp = atomicAdd(&pool_cnt, 1u);                         \
            if (pp < POOL) { pool[pp] = key; qflag[l] = 1u; }                   \
            else qover[l] = 1u;                                                 \
          }                                                                     \
        }                                                                       \
      }                                                                         \
    }
    for (int i = 0; i < 512; i += 8) {
      float4 cA0 = pA0; pA0 = xb[base + i + 8];
      float4 cA1 = pA1; pA1 = xb[base + i + 9];
      float4 cA2 = pA2; pA2 = xb[base + i + 10];
      float4 cA3 = pA3; pA3 = xb[base + i + 11];
      COLLECT(cA0, base + i)     COLLECT(cA1, base + i + 1)
      COLLECT(cA2, base + i + 2) COLLECT(cA3, base + i + 3)
      float4 cB0 = pB0; pB0 = xb[base + i + 12];
      float4 cB1 = pB1; pB1 = xb[base + i + 13];
      float4 cB2 = pB2; pB2 = xb[base + i + 14];
      float4 cB3 = pB3; pB3 = xb[base + i + 15];
      COLLECT(cB0, base + i + 4) COLLECT(cB1, base + i + 5)
      COLLECT(cB2, base + i + 6) COLLECT(cB3, base + i + 7)
    }
#undef COLLECT
  }
#undef KF
  __syncthreads();

  // ---- P3: parallel top-20 (16 lanes per query, 64 queries) ----
  const int qg = t >> 4, sub = t & 15;
  unsigned int n = qcnt[qg]; if (n > CAP) n = CAP;
  const unsigned int pcnt = (qflag[qg] && !qover[qg]) ? min(pool_cnt, (unsigned int)POOL) : 0u;
  unsigned short* oq = nidx + ((size_t)(batch * N_PTS + q0 + qg)) * KNN;

  if (qover[qg]) {
    if (sub == 0) {
      // exact serial fallback (astronomically rare)
      unsigned long long best[KNN];
#pragma unroll
      for (int j = 0; j < KNN; ++j) best[j] = ~0ULL;
      const float4 qv2 = xb[q0 + qg];
      for (int m = 0; m < N_PTS; ++m) {
        float dist = qdist2(qv2, xb[m]);
        unsigned long long p = ((unsigned long long)distbits(dist) << 32) | (unsigned int)m;
        if (p < best[KNN - 1]) {
          int j = KNN - 1;
          while (j > 0 && best[j - 1] > p) { best[j] = best[j - 1]; --j; }
          best[j] = p;
        }
      }
      for (int j = 0; j < KNN; ++j) oq[j] = (unsigned short)(best[j] & 0xffffu);
    }
  } else {
    for (int r = 0; r < KNN; ++r) {
      unsigned long long best = ~0ULL; int bslot = 0;
      for (unsigned int s = sub; s < n; s += 16) {
        unsigned long long v = ((unsigned long long)lst_d[qg * STQ + s] << 16)
                             | (unsigned long long)lst_i[qg * STQ + s];
        if (v < best) { best = v; bslot = (int)s; }
      }
      for (unsigned int s = sub; s < pcnt; s += 16) {
        unsigned long long v = pool[s];
        if ((unsigned int)((v >> 16) & 0xffffu) == (unsigned int)qg) {
          unsigned long long pv = ((v >> 32) << 16) | (v & 0xffffULL);
          if (pv < best) { best = pv; bslot = 0x10000 | (int)s; }
        }
      }
#pragma unroll
      for (int mm = 1; mm < 16; mm <<= 1) {
        unsigned long long ob = __shfl_xor(best, mm, 64);
        int obs = __shfl_xor(bslot, mm, 64);
        if (ob < best) { best = ob; bslot = obs; }
      }
      int s = bslot & 0xffff;
      if ((s & 15) == sub) {
        if (bslot & 0x10000) pool[s] = ~0ULL;
        else lst_d[qg * STQ + s] = 0xFFFFFFFFu;   // sentinel > any finite distbits
      }
      if (sub == 0) oq[r] = (unsigned short)(best & 0xffffu);
    }
  }
}

// ======================================================================
// Kernel 2: covariance (sorted order) + eigh -> normals (r9 verbatim)
// ======================================================================
__global__ __launch_bounds__(64) void normals_kernel(const float4* __restrict__ xyz4,
                                                     const unsigned short* __restrict__ nidx,
                                                     float4* __restrict__ nrm4) {
  int gid = blockIdx.x * 64 + threadIdx.x;
  int batch = gid >> 13, q = gid & (N_PTS - 1);
  const float4* __restrict__ xb = xyz4 + batch * N_PTS;
  const float4 qv = xb[q];
  const unsigned short* iq = nidx + (size_t)gid * KNN;
  float c00, c01, c02, c11, c12, c22;
  {
#pragma clang fp contract(off)
    c00 = 0.f; c01 = 0.f; c02 = 0.f; c11 = 0.f; c12 = 0.f; c22 = 0.f;
    for (int j = 0; j < KNN; ++j) {
      float4 pv = xb[iq[j]];
      float dx = pv.x - qv.x, dy = pv.y - qv.y, dz = pv.z - qv.z;
      c00 = c00 + dx * dx; c01 = c01 + dx * dy; c02 = c02 + dx * dz;
      c11 = c11 + dy * dy; c12 = c12 + dy * dz; c22 = c22 + dz * dz;
    }
  }
  float ev[3];
  eigh3_smallest(c00, c01, c02, c11, c12, c22, ev);
  nrm4[gid] = make_float4(ev[0], ev[1], ev[2], 0.0f);
}

// ======================================================================
// Kernel 3: GEMM1 + BN stats (+ optional h store for the bn_out path)
// ======================================================================
__global__ __launch_bounds__(256) void gemm1_stats_kernel(const float* __restrict__ x,
                                                          const float4* __restrict__ nrm4,
                                                          const float* __restrict__ w1t,
                                                          const float* __restrict__ b1,
                                                          float* __restrict__ sums,
                                                          float* __restrict__ sumsq,
                                                          float* __restrict__ h) {
  __shared__ float lds[64 * 134];
  const int t = threadIdx.x;
  const int b = blockIdx.x >> 7;
  const int n0 = (blockIdx.x & 127) << 6;
  for (int idx = t; idx < CH * 64; idx += 256) {
    int cc = idx >> 6, nl = idx & 63;
    lds[nl * 134 + cc] = x[((size_t)(b * CH + cc)) * N_PTS + n0 + nl];
  }
  if (t < 64) {
    float4 nv = nrm4[b * N_PTS + n0 + t];
    lds[t * 134 + 128] = nv.x; lds[t * 134 + 129] = nv.y;
    lds[t * 134 + 130] = nv.z; lds[t * 134 + 131] = 0.0f;
  }
  __syncthreads();

  const int og = __builtin_amdgcn_readfirstlane(t >> 6);
  const int nl = t & 63;
  float acc[32];
#pragma unroll
  for (int k = 0; k < 32; ++k) acc[k] = b1[og * 32 + k];
  for (int c2 = 0; c2 < 66; ++c2) {
    float2 xv = *(const float2*)&lds[nl * 134 + 2 * c2];
    const float* wr0 = w1t + (2 * c2) * CH + og * 32;
    const float* wr1 = wr0 + CH;
#pragma unroll
    for (int k = 0; k < 32; ++k) acc[k] = fmaf(wr0[k], xv.x, acc[k]);
#pragma unroll
    for (int k = 0; k < 32; ++k) acc[k] = fmaf(wr1[k], xv.y, acc[k]);
  }
  if (h != nullptr) {
#pragma unroll
    for (int k = 0; k < 32; ++k) {
      int o = og * 32 + k;
      h[((size_t)(b * CH + o)) * N_PTS + n0 + nl] = acc[k];
    }
  }
  __syncthreads();
#pragma unroll
  for (int k2 = 0; k2 < 16; ++k2)
    *(float2*)&lds[nl * 134 + og * 32 + 2 * k2] = make_float2(acc[2 * k2], acc[2 * k2 + 1]);
  __syncthreads();
  {
    int cc = t & 127, hf = t >> 7;
    float sm = 0.f, sq = 0.f;
    for (int rr = hf * 32; rr < hf * 32 + 32; ++rr) {
      float v = lds[rr * 134 + cc];
      sm += v; sq = fmaf(v, v, sq);
    }
    atomicAdd(&sums[cc], sm);
    atomicAdd(&sumsq[cc], sq);
  }
}

// ======================================================================
// Kernel 4: finalize BN scale/shift (fallback path only)
// ======================================================================
__global__ void bn_finalize_kernel(const float* __restrict__ sums, const float* __restrict__ sumsq,
                                   const float* __restrict__ gamma, const float* __restrict__ beta,
                                   float* __restrict__ scale, float* __restrict__ shift) {
  int c = threadIdx.x;
  if (c < CH) {
    const double cnt = (double)(BATCH * N_PTS);
    double mean = (double)sums[c] / cnt;
    double var = (double)sumsq[c] / cnt - mean * mean;
    double inv = 1.0 / sqrt(var + 1e-5);
    double sc = (double)gamma[c] * inv;
    scale[c] = (float)sc;
    shift[c] = (float)((double)beta[c] - mean * sc);
  }
}

// ======================================================================
// Kernel 5 (primary): BN(inline scale/shift) + ReLU + GEMM2 from stored h
// — skips the GEMM1 recompute and the bn_finalize dispatch.
// scale/shift math verbatim (double precision, same inputs) => same bits;
// h bits == the acc bits fused_out would recompute => output bit-identical.
// ======================================================================
__global__ __launch_bounds__(256) void bn_out_kernel(const float* __restrict__ h,
                                                     const float* __restrict__ w2t,
                                                     const float* __restrict__ b2,
                                                     const float* __restrict__ sums,
                                                     const float* __restrict__ sumsq,
                                                     const float* __restrict__ gamma,
                                                     const float* __restrict__ beta,
                                                     float* __restrict__ out) {
  __shared__ float lds[64 * 134];
  __shared__ float s_scale[CH];
  __shared__ float s_shift[CH];
  const int t = threadIdx.x;
  const int b = blockIdx.x >> 7;
  const int n0 = (blockIdx.x & 127) << 6;
  if (t < CH) {
    const double cnt = (double)(BATCH * N_PTS);
    double mean = (double)sums[t] / cnt;
    double var = (double)sumsq[t] / cnt - mean * mean;
    double inv = 1.0 / sqrt(var + 1e-5);
    double sc = (double)gamma[t] * inv;
    s_scale[t] = (float)sc;
    s_shift[t] = (float)((double)beta[t] - mean * sc);
  }
  for (int idx = t; idx < CH * 64; idx += 256) {
    int cc = idx >> 6, nl = idx & 63;
    lds[nl * 134 + cc] = h[((size_t)(b * CH + cc)) * N_PTS + n0 + nl];
  }
  __syncthreads();
  // apply BN + ReLU in LDS (same formula/values as fused_out's register path)
  for (int idx = t; idx < CH * 64; idx += 256) {
    int cc = idx >> 6, nl = idx & 63;
    float v = lds[nl * 134 + cc];
    lds[nl * 134 + cc] = fmaxf(fmaf(v, s_scale[cc], s_shift[cc]), 0.0f);
  }
  __syncthreads();

  const int og = __builtin_amdgcn_readfirstlane(t >> 6);
  const int nl = t & 63;
  float acc2[32];
#pragma unroll
  for (int k = 0; k < 32; ++k) acc2[k] = b2[og * 32 + k];
  for (int c2 = 0; c2 < 64; ++c2) {
    float2 hv = *(const float2*)&lds[nl * 134 + 2 * c2];
    const float* wr0 = w2t + (2 * c2) * CH + og * 32;
    const float* wr1 = wr0 + CH;
#pragma unroll
    for (int k = 0; k < 32; ++k) acc2[k] = fmaf(wr0[k], hv.x, acc2[k]);
#pragma unroll
    for (int k = 0; k < 32; ++k) acc2[k] = fmaf(wr1[k], hv.y, acc2[k]);
  }
#pragma unroll
  for (int k = 0; k < 32; ++k) {
    int o = og * 32 + k;
    out[((size_t)(b * CH + o)) * N_PTS + n0 + nl] = acc2[k];
  }
}

// ======================================================================
// Kernel 5b (fallback, ws too small): original fused GEMM1+BN+ReLU+GEMM2
// ======================================================================
__global__ __launch_bounds__(256) void fused_out_kernel(const float* __restrict__ x,
                                                        const float4* __restrict__ nrm4,
                                                        const float* __restrict__ w1t,
                                                        const float* __restrict__ b1,
                                                        const float* __restrict__ w2t,
                                                        const float* __restrict__ b2,
                                                        const float* __restrict__ scale,
                                                        const float* __restrict__ shift,
                                                        float* __restrict__ out) {
  __shared__ float lds[64 * 134];
  const int t = threadIdx.x;
  const int b = blockIdx.x >> 7;
  const int n0 = (blockIdx.x & 127) << 6;
  for (int idx = t; idx < CH * 64; idx += 256) {
    int cc = idx >> 6, nl = idx & 63;
    lds[nl * 134 + cc] = x[((size_t)(b * CH + cc)) * N_PTS + n0 + nl];
  }
  if (t < 64) {
    float4 nv = nrm4[b * N_PTS + n0 + t];
    lds[t * 134 + 128] = nv.x; lds[t * 134 + 129] = nv.y;
    lds[t * 134 + 130] = nv.z; lds[t * 134 + 131] = 0.0f;
  }
  __syncthreads();

  const int og = __builtin_amdgcn_readfirstlane(t >> 6);
  const int nl = t & 63;
  float acc[32];
#pragma unroll
  for (int k = 0; k < 32; ++k) acc[k] = b1[og * 32 + k];
  for (int c2 = 0; c2 < 66; ++c2) {
    float2 xv = *(const float2*)&lds[nl * 134 + 2 * c2];
    const float* wr0 = w1t + (2 * c2) * CH + og * 32;
    const float* wr1 = wr0 + CH;
#pragma unroll
    for (int k = 0; k < 32; ++k) acc[k] = fmaf(wr0[k], xv.x, acc[k]);
#pragma unroll
    for (int k = 0; k < 32; ++k) acc[k] = fmaf(wr1[k], xv.y, acc[k]);
  }
#pragma unroll
  for (int k = 0; k < 32; ++k) {
    float sc = scale[og * 32 + k], sh = shift[og * 32 + k];
    acc[k] = fmaxf(fmaf(acc[k], sc, sh), 0.0f);
  }
  __syncthreads();
#pragma unroll
  for (int k2 = 0; k2 < 16; ++k2)
    *(float2*)&lds[nl * 134 + og * 32 + 2 * k2] = make_float2(acc[2 * k2], acc[2 * k2 + 1]);
  __syncthreads();

  float acc2[32];
#pragma unroll
  for (int k = 0; k < 32; ++k) acc2[k] = b2[og * 32 + k];
  for (int c2 = 0; c2 < 64; ++c2) {
    float2 hv = *(const float2*)&lds[nl * 134 + 2 * c2];
    const float* wr0 = w2t + (2 * c2) * CH + og * 32;
    const float* wr1 = wr0 + CH;
#pragma unroll
    for (int k = 0; k < 32; ++k) acc2[k] = fmaf(wr0[k], hv.x, acc2[k]);
#pragma unroll
    for (int k = 0; k < 32; ++k) acc2[k] = fmaf(wr1[k], hv.y, acc2[k]);
  }
#pragma unroll
  for (int k = 0; k < 32; ++k) {
    int o = og * 32 + k;
    out[((size_t)(b * CH + o)) * N_PTS + n0 + nl] = acc2[k];
  }
}

// ======================================================================
extern "C" void kernel_launch(void* const* d_in, const int* in_sizes, int n_in,
                              void* d_out, int out_size, void* d_ws, size_t ws_size,
                              hipStream_t stream) {
  const float* x     = (const float*)d_in[0];
  const float* xyz   = (const float*)d_in[1];
  const float* w1    = (const float*)d_in[2];
  const float* b1    = (const float*)d_in[3];
  const float* gamma = (const float*)d_in[4];
  const float* beta  = (const float*)d_in[5];
  const float* w2    = (const float*)d_in[6];
  const float* b2    = (const float*)d_in[7];
  float* out = (float*)d_out;

  float* W = (float*)d_ws;
  float4* xyz4 = (float4*)W;                         // floats [0, 131072)
  float4* nrm4 = (float4*)(W + 131072);              // floats [131072, 262144)
  float* w1t   = W + 262144;                         // [262144, 279040)
  float* w2t   = W + 279040;                         // [279040, 295424)
  float* stats = W + 295424;                         // [295424, 295680)
  float* scale = W + 295680;                         // [295680, 295808)
  float* shift = W + 295808;                         // [295808, 295936)
  unsigned short* nidx = (unsigned short*)(W + 295936);  // 32768*20 u16 = 327680 floats -> ends 623616
  float* h     = W + 624640;                         // 4*128*8192 floats = 16.78 MB (16B-aligned)

  const size_t need = (size_t)(624640 + (size_t)BATCH * CH * N_PTS) * 4;
  const bool use_h = (ws_size >= need);

  prep_kernel<<<128, 256, 0, stream>>>(xyz, w1, w2, xyz4, w1t, w2t, stats);
  knn_select_kernel<<<BATCH * N_PTS / 64, 1024, 0, stream>>>(xyz4, nidx);
  normals_kernel<<<BATCH * N_PTS / 64, 64, 0, stream>>>(xyz4, nidx, nrm4);
  gemm1_stats_kernel<<<BATCH * N_PTS / 64, 256, 0, stream>>>(x, nrm4, w1t, b1, stats, stats + 128,
                                                             use_h ? h : nullptr);
  if (use_h) {
    bn_out_kernel<<<BATCH * N_PTS / 64, 256, 0, stream>>>(h, w2t, b2, stats, stats + 128,
                                                          gamma, beta, out);
  } else {
    bn_finalize_kernel<<<1, 128, 0, stream>>>(stats, stats + 128, gamma, beta, scale, shift);
    fused_out_kernel<<<BATCH * N_PTS / 64, 256, 0, stream>>>(x, nrm4, w1t, b1, w2t, b2, scale, shift, out);
  }
}

// Round 14
// 334.925 us; speedup vs baseline: 1.1320x; 1.0495x over previous
//
#include <hip/hip_runtime.h>
#include <math.h>

#define N_PTS 8192
#define BATCH 4
#define CH 128
#define KNN 20
#define CAP 112
#define STQ 114
#define POOL 256

// ======================================================================
// LAPACK ssyevd emulation for 3x3 symmetric (lower), SINGLE precision,
// matching numpy's float32 eigh path bit-for-bit where decisions matter.
// (verified passing — do not perturb numerics)
// ======================================================================

__device__ __forceinline__ float slapy2f(float x, float y) {
#pragma clang fp contract(off)
  float ax = fabsf(x), ay = fabsf(y);
  float w = fmaxf(ax, ay), z = fminf(ax, ay);
  if (z == 0.0f) return w;
  float t = z / w;
  return w * sqrtf(1.0f + t * t);
}

__device__ __forceinline__ void slartgf(float f, float g, float* cs, float* sn, float* r) {
#pragma clang fp contract(off)
  if (g == 0.0f) { *cs = 1.0f; *sn = 0.0f; *r = f; }
  else if (f == 0.0f) { *cs = 0.0f; *sn = copysignf(1.0f, g); *r = fabsf(g); }
  else {
    float f1 = fabsf(f);
    float d = sqrtf(f * f + g * g);
    *cs = f1 / d;
    *r = copysignf(d, f);
    *sn = g / (*r);
  }
}

__device__ void slaev2f(float a, float b, float c, float* rt1, float* rt2,
                        float* cs1, float* sn1) {
#pragma clang fp contract(off)
  float sm = a + c, df = a - c, adf = fabsf(df);
  float tb = b + b, ab = fabsf(tb);
  float acmx, acmn;
  if (fabsf(a) > fabsf(c)) { acmx = a; acmn = c; } else { acmx = c; acmn = a; }
  float rt;
  if (adf > ab)      { float q = ab / adf;  rt = adf * sqrtf(1.0f + q * q); }
  else if (adf < ab) { float q = adf / ab;  rt = ab * sqrtf(1.0f + q * q); }
  else               rt = ab * sqrtf(2.0f);
  int sgn1;
  if (sm < 0.0f)      { *rt1 = 0.5f * (sm - rt); sgn1 = -1; *rt2 = (acmx / *rt1) * acmn - (b / *rt1) * b; }
  else if (sm > 0.0f) { *rt1 = 0.5f * (sm + rt); sgn1 = 1;  *rt2 = (acmx / *rt1) * acmn - (b / *rt1) * b; }
  else                { *rt1 = 0.5f * rt; *rt2 = -0.5f * rt; sgn1 = 1; }
  float cs; int sgn2;
  if (df >= 0.0f) { cs = df + rt; sgn2 = 1; } else { cs = df - rt; sgn2 = -1; }
  float acs = fabsf(cs);
  if (acs > ab) {
    float ct = -tb / cs;
    *sn1 = 1.0f / sqrtf(1.0f + ct * ct);
    *cs1 = ct * (*sn1);
  } else {
    if (ab == 0.0f) { *cs1 = 1.0f; *sn1 = 0.0f; }
    else {
      float tn = -cs / tb;
      *cs1 = 1.0f / sqrtf(1.0f + tn * tn);
      *sn1 = tn * (*cs1);
    }
  }
  if (sgn1 == sgn2) { float tn = *cs1; *cs1 = -(*sn1); *sn1 = tn; }
}

__device__ void eigh3_smallest(float a00, float a10, float a20,
                               float a11, float a21, float a22, float evec[3]) {
#pragma clang fp contract(off)
  float d[3], e[2], tau = 0.0f, v2 = 0.0f;
  d[0] = a00;
  {
    float xnorm = sqrtf(a20 * a20);   // snrm2(1)
    if (xnorm == 0.0f) {
      tau = 0.0f; v2 = 0.0f;
      e[0] = a10; d[1] = a11; e[1] = a21; d[2] = a22;
    } else {
      float alpha = a10;
      float beta = -copysignf(slapy2f(alpha, xnorm), alpha);
      tau = (beta - alpha) / beta;
      float invs = 1.0f / (alpha - beta);
      v2 = a20 * invs;
      e[0] = beta;
      float y0 = tau * a11;
      float y1 = tau * a21;
      y0 = y0 + tau * (a21 * v2);
      y1 = y1 + (tau * v2) * a22;
      float dot = y0 + y1 * v2;
      float al = (-0.5f * tau) * dot;
      float w0 = y0 + al;
      float w1 = y1 + al * v2;
      a11 = (a11 - w0) - w0;
      a21 = (a21 - v2 * w0) - w1;
      a22 = (a22 - v2 * w1) - w1 * v2;
      d[1] = a11; e[1] = a21; d[2] = a22;
    }
  }

  float z[3][3] = {{1.0f,0.0f,0.0f},{0.0f,1.0f,0.0f},{0.0f,0.0f,1.0f}};
  const float eps = 5.9604644775390625e-08f;
  const float eps2 = 3.5527136788005009e-15f;
  const float safmin = 1.1754943508222875e-38f;
  int nmaxit = 90, jtot = 0;
  int l1 = 0;
  int l, m, lend, lsv, lendsv;
  float p, g, r, c, s, f, b_, rt1, rt2, tst;
  float wc[2], wsn[2];

outer_loop:
  if (l1 > 2) goto sorting;
  if (l1 > 0) e[l1 - 1] = 0.0f;
  {
    int mm;
    for (mm = l1; mm <= 1; ++mm) {
      tst = fabsf(e[mm]);
      if (tst == 0.0f) break;
      if (tst <= (sqrtf(fabsf(d[mm])) * sqrtf(fabsf(d[mm + 1]))) * eps) { e[mm] = 0.0f; break; }
    }
    m = (mm > 1) ? 2 : mm;
  }
  l = l1; lsv = l; lend = m; lendsv = lend; l1 = m + 1;
  if (lend == l) goto outer_loop;
  {
    float an = 0.0f;
    for (int i2 = l; i2 <= lend; ++i2) an = fmaxf(an, fabsf(d[i2]));
    for (int i2 = l; i2 < lend; ++i2) an = fmaxf(an, fabsf(e[i2]));
    if (an == 0.0f) goto outer_loop;
  }
  if (fabsf(d[lend]) < fabsf(d[l])) { lend = lsv; l = lendsv; }

  if (lend > l) {
ql40:
    if (l != lend) {
      for (m = l; m <= lend - 1; ++m) {
        tst = e[m] * e[m];
        if (tst <= (eps2 * fabsf(d[m])) * fabsf(d[m + 1]) + safmin) goto ql60;
      }
    }
    m = lend;
ql60:
    if (m < lend) e[m] = 0.0f;
    p = d[l];
    if (m == l) goto ql80;
    if (m == l + 1) {
      slaev2f(d[l], e[l], d[l + 1], &rt1, &rt2, &c, &s);
      for (int i2 = 0; i2 < 3; ++i2) {
        float temp = z[i2][l + 1];
        z[i2][l + 1] = c * temp - s * z[i2][l];
        z[i2][l]     = s * temp + c * z[i2][l];
      }
      d[l] = rt1; d[l + 1] = rt2; e[l] = 0.0f;
      l += 2;
      if (l <= lend) goto ql40;
      goto done140;
    }
    if (jtot == nmaxit) goto done140;
    jtot++;
    g = (d[l + 1] - p) / (2.0f * e[l]);
    r = slapy2f(g, 1.0f);
    g = d[m] - p + e[l] / (g + copysignf(r, g));
    s = 1.0f; c = 1.0f; p = 0.0f;
    for (int i2 = m - 1; i2 >= l; --i2) {
      f = s * e[i2]; b_ = c * e[i2];
      slartgf(g, f, &c, &s, &r);
      if (i2 != m - 1) e[i2 + 1] = r;
      g = d[i2 + 1] - p;
      r = (d[i2] - g) * s + 2.0f * c * b_;
      p = s * r;
      d[i2 + 1] = g + p;
      g = c * r - b_;
      wc[i2] = c; wsn[i2] = -s;
    }
    for (int j = m - 1; j >= l; --j) {
      float ct = wc[j], st = wsn[j];
      for (int i2 = 0; i2 < 3; ++i2) {
        float temp = z[i2][j + 1];
        z[i2][j + 1] = ct * temp - st * z[i2][j];
        z[i2][j]     = st * temp + ct * z[i2][j];
      }
    }
    d[l] -= p;
    e[l] = g;
    goto ql40;
ql80:
    d[l] = p;
    l += 1;
    if (l <= lend) goto ql40;
    goto done140;
  } else {
qr90:
    if (l != lend) {
      for (m = l; m >= lend + 1; --m) {
        tst = e[m - 1] * e[m - 1];
        if (tst <= (eps2 * fabsf(d[m])) * fabsf(d[m - 1]) + safmin) goto qr110;
      }
    }
    m = lend;
qr110:
    if (m > lend) e[m - 1] = 0.0f;
    p = d[l];
    if (m == l) goto qr130;
    if (m == l - 1) {
      slaev2f(d[l - 1], e[l - 1], d[l], &rt1, &rt2, &c, &s);
      for (int i2 = 0; i2 < 3; ++i2) {
        float temp = z[i2][l];
        z[i2][l]     = c * temp - s * z[i2][l - 1];
        z[i2][l - 1] = s * temp + c * z[i2][l - 1];
      }
      d[l - 1] = rt1; d[l] = rt2; e[l - 1] = 0.0f;
      l -= 2;
      if (l >= lend) goto qr90;
      goto done140;
    }
    if (jtot == nmaxit) goto done140;
    jtot++;
    g = (d[l - 1] - p) / (2.0f * e[l - 1]);
    r = slapy2f(g, 1.0f);
    g = d[m] - p + e[l - 1] / (g + copysignf(r, g));
    s = 1.0f; c = 1.0f; p = 0.0f;
    for (int i2 = m; i2 <= l - 1; ++i2) {
      f = s * e[i2]; b_ = c * e[i2];
      slartgf(g, f, &c, &s, &r);
      if (i2 != m) e[i2 - 1] = r;
      g = d[i2] - p;
      r = (d[i2 + 1] - g) * s + 2.0f * c * b_;
      p = s * r;
      d[i2] = g + p;
      g = c * r - b_;
      wc[i2] = c; wsn[i2] = s;
    }
    for (int j = m; j <= l - 1; ++j) {
      float ct = wc[j], st = wsn[j];
      for (int i2 = 0; i2 < 3; ++i2) {
        float temp = z[i2][j + 1];
        z[i2][j + 1] = ct * temp - st * z[i2][j];
        z[i2][j]     = st * temp + ct * z[i2][j];
      }
    }
    d[l] -= p;
    e[l - 1] = g;
    goto qr90;
qr130:
    d[l] = p;
    l -= 1;
    if (l >= lend) goto qr90;
    goto done140;
  }
done140:
  if (jtot < nmaxit) goto outer_loop;
sorting:
  for (int ii = 1; ii <= 2; ++ii) {
    int i_ = ii - 1, k = i_;
    p = d[i_];
    for (int j = ii; j <= 2; ++j) if (d[j] < p) { k = j; p = d[j]; }
    if (k != i_) {
      d[k] = d[i_]; d[i_] = p;
      for (int i2 = 0; i2 < 3; ++i2) { float tz = z[i2][i_]; z[i2][i_] = z[i2][k]; z[i2][k] = tz; }
    }
  }
  {
    float z10 = z[1][0], z20 = z[2][0];
    float sum = z10 + v2 * z20;
    evec[0] = z[0][0];
    evec[1] = z10 - tau * sum;
    evec[2] = z20 - tau * sum * v2;
  }
}

// ======================================================================
// Kernel 0: prep
// xyz4.w holds -0.5*|p|^2 (EXACT: power-of-2 scale). |p|^2 recoverable
// bit-exactly as -2*w => exact-distance formula downstream bit-identical.
// ======================================================================
__global__ __launch_bounds__(256) void prep_kernel(const float* __restrict__ xyz,
                                                   const float* __restrict__ w1,
                                                   const float* __restrict__ w2,
                                                   float4* __restrict__ xyz4,
                                                   float* __restrict__ w1t,
                                                   float* __restrict__ w2t,
                                                   float* __restrict__ stats) {
  int idx = blockIdx.x * 256 + threadIdx.x;
  if (idx < BATCH * N_PTS) {
    float x = xyz[idx * 3], y = xyz[idx * 3 + 1], zz = xyz[idx * 3 + 2];
    float sq = fmaf(zz, zz, fmaf(y, y, x * x));
    xyz4[idx] = make_float4(x, y, zz, -0.5f * sq);
  }
  if (idx < 132 * CH) {
    int cc = idx >> 7, o = idx & 127;
    w1t[idx] = (cc < 131) ? w1[o * 131 + cc] : 0.0f;
  }
  if (idx < CH * CH) {
    int cc = idx >> 7, o = idx & 127;
    w2t[idx] = w2[o * CH + cc];
  }
  if (idx < 256) stats[idx] = 0.0f;
}

// exact dist, bit-identical to original qdist (w fields hold -0.5*sq)
__device__ __forceinline__ float qdist2(const float4 qv, const float4 cv) {
  float dot = fmaf(qv.x, cv.x, fmaf(qv.y, cv.y, qv.z * cv.z));
  return fmaf(-2.0f, dot, (-2.0f * qv.w) + (-2.0f * cv.w));
}

__device__ __forceinline__ unsigned int distbits(float dist) {
  unsigned int du = __float_as_uint(dist);
  return (du & 0x80000000u) ? ~du : (du | 0x80000000u);  // monotone total order
}

// ======================================================================
// Kernel 1: exact 20-NN — r9 verbatim (proven 181us).
// ======================================================================
__global__ __launch_bounds__(1024, 8) void knn_select_kernel(const float4* __restrict__ xyz4,
                                                             unsigned short* __restrict__ nidx) {
  __shared__ unsigned int lst_d[64 * STQ];      // 29184 B
  __shared__ unsigned short lst_i[64 * STQ];    // 14592 B
  __shared__ float2 bnd[16 * 64];               // 8192 B (top-2 per wave,lane)
  __shared__ unsigned long long pool[POOL];     // 2048 B
  __shared__ unsigned int qcnt[64];
  __shared__ unsigned int qflag[64];
  __shared__ unsigned int qover[64];
  __shared__ unsigned int pool_cnt;

  const int t = threadIdx.x;
  const int w = t >> 6, l = t & 63;
  const int batch = blockIdx.x >> 7;               // 128 blocks per batch
  const int q0 = (blockIdx.x & 127) << 6;          // 64 queries per block
  const float4* __restrict__ xb = xyz4 + batch * N_PTS;
  const float4 qv = xb[q0 + l];
  const float qw = -2.0f * qv.w;                   // exact |q|^2

  if (t < 64) { qcnt[t] = 0; qflag[t] = 0; qover[t] = 0; }
  if (t == 0) pool_cnt = 0;

  const int base = __builtin_amdgcn_readfirstlane(w * 512);

#define KF(cv) fmaf(qv.x, (cv).x, fmaf(qv.y, (cv).y, fmaf(qv.z, (cv).z, (cv).w)))

  // ---- P1: top-2-largest k over this wave's 512 pts (dual buffer) ----
  float a0 = -INFINITY, a1 = -INFINITY;
  {
    float4 pA0 = xb[base + 0], pA1 = xb[base + 1], pA2 = xb[base + 2], pA3 = xb[base + 3];
    float4 pB0 = xb[base + 4], pB1 = xb[base + 5], pB2 = xb[base + 6], pB3 = xb[base + 7];
#define TOP2(kk) { float tt = fminf(a0, kk); a0 = fmaxf(a0, kk); a1 = fmaxf(a1, tt); }
    for (int i = 0; i < 512; i += 8) {
      float k0 = KF(pA0); pA0 = xb[base + i + 8];
      float k1 = KF(pA1); pA1 = xb[base + i + 9];
      float k2 = KF(pA2); pA2 = xb[base + i + 10];
      float k3 = KF(pA3); pA3 = xb[base + i + 11];
      TOP2(k0) TOP2(k1) TOP2(k2) TOP2(k3)
      k0 = KF(pB0); pB0 = xb[base + i + 12];
      k1 = KF(pB1); pB1 = xb[base + i + 13];
      k2 = KF(pB2); pB2 = xb[base + i + 14];
      k3 = KF(pB3); pB3 = xb[base + i + 15];
      TOP2(k0) TOP2(k1) TOP2(k2) TOP2(k3)
    }
#undef TOP2
  }
  bnd[w * 64 + l] = make_float2(a0, a1);
  __syncthreads();

  // per-1024-group exact 3rd-largest of the 4 wave-pair candidates
  float kmin = INFINITY;
#pragma unroll
  for (int g = 0; g < 8; ++g) {
    float2 pa = bnd[(2 * g) * 64 + l];
    float2 pb = bnd[(2 * g + 1) * 64 + l];
    float third = fmaxf(fminf(pa.y, pb.x), fminf(pa.x, pb.y));
    kmin = fminf(kmin, third);
  }
  float Tq = fmaf(-2.0f, kmin, qw);
  Tq = Tq + (fabsf(Tq) * 2e-5f + 1e-3f);           // rounding slack (>>3e-5 worst case)
  const float thK = 0.5f * (qw - Tq) - 1e-3f;      // prefilter: k>=thK <=> dist_k<=Tq+2e-3

  // ---- P2: collect (dual buffer + 3-fma prefilter) ----
  {
    float4 pA0 = xb[base + 0], pA1 = xb[base + 1], pA2 = xb[base + 2], pA3 = xb[base + 3];
    float4 pB0 = xb[base + 4], pB1 = xb[base + 5], pB2 = xb[base + 6], pB3 = xb[base + 7];
#define COLLECT(cv, idx_) {                                                     \
      float k = KF(cv);                                                         \
      if (k >= thK) {                                                           \
        float dot = fmaf(qv.x, (cv).x, fmaf(qv.y, (cv).y, qv.z * (cv).z));      \
        float dist = fmaf(-2.0f, dot, qw + (-2.0f * (cv).w));                   \
        if (dist <= Tq) {                                                       \
          unsigned int db = distbits(dist);                                     \
          unsigned int pos = atomicAdd(&qcnt[l], 1u);                           \
          if (pos < CAP) {                                                      \
            lst_d[l * STQ + pos] = db;                                          \
            lst_i[l * STQ + pos] = (unsigned short)(idx_);                      \
          } else {                                                              \
            unsigned long long key = ((unsigned long long)db << 32)             \
                                   | ((unsigned int)l << 16) | (unsigned int)(idx_); \
            unsigned int pp = atomicAdd(&pool_cnt, 1u);                         \
            if (pp < POOL) { pool[pp] = key; qflag[l] = 1u; }                   \
            else qover[l] = 1u;                                                 \
          }                                                                     \
        }                                                                       \
      }                                                                         \
    }
    for (int i = 0; i < 512; i += 8) {
      float4 cA0 = pA0; pA0 = xb[base + i + 8];
      float4 cA1 = pA1; pA1 = xb[base + i + 9];
      float4 cA2 = pA2; pA2 = xb[base + i + 10];
      float4 cA3 = pA3; pA3 = xb[base + i + 11];
      COLLECT(cA0, base + i)     COLLECT(cA1, base + i + 1)
      COLLECT(cA2, base + i + 2) COLLECT(cA3, base + i + 3)
      float4 cB0 = pB0; pB0 = xb[base + i + 12];
      float4 cB1 = pB1; pB1 = xb[base + i + 13];
      float4 cB2 = pB2; pB2 = xb[base + i + 14];
      float4 cB3 = pB3; pB3 = xb[base + i + 15];
      COLLECT(cB0, base + i + 4) COLLECT(cB1, base + i + 5)
      COLLECT(cB2, base + i + 6) COLLECT(cB3, base + i + 7)
    }
#undef COLLECT
  }
#undef KF
  __syncthreads();

  // ---- P3: parallel top-20 (16 lanes per query, 64 queries) ----
  const int qg = t >> 4, sub = t & 15;
  unsigned int n = qcnt[qg]; if (n > CAP) n = CAP;
  const unsigned int pcnt = (qflag[qg] && !qover[qg]) ? min(pool_cnt, (unsigned int)POOL) : 0u;
  unsigned short* oq = nidx + ((size_t)(batch * N_PTS + q0 + qg)) * KNN;

  if (qover[qg]) {
    if (sub == 0) {
      // exact serial fallback (astronomically rare)
      unsigned long long best[KNN];
#pragma unroll
      for (int j = 0; j < KNN; ++j) best[j] = ~0ULL;
      const float4 qv2 = xb[q0 + qg];
      for (int m = 0; m < N_PTS; ++m) {
        float dist = qdist2(qv2, xb[m]);
        unsigned long long p = ((unsigned long long)distbits(dist) << 32) | (unsigned int)m;
        if (p < best[KNN - 1]) {
          int j = KNN - 1;
          while (j > 0 && best[j - 1] > p) { best[j] = best[j - 1]; --j; }
          best[j] = p;
        }
      }
      for (int j = 0; j < KNN; ++j) oq[j] = (unsigned short)(best[j] & 0xffffu);
    }
  } else {
    for (int r = 0; r < KNN; ++r) {
      unsigned long long best = ~0ULL; int bslot = 0;
      for (unsigned int s = sub; s < n; s += 16) {
        unsigned long long v = ((unsigned long long)lst_d[qg * STQ + s] << 16)
                             | (unsigned long long)lst_i[qg * STQ + s];
        if (v < best) { best = v; bslot = (int)s; }
      }
      for (unsigned int s = sub; s < pcnt; s += 16) {
        unsigned long long v = pool[s];
        if ((unsigned int)((v >> 16) & 0xffffu) == (unsigned int)qg) {
          unsigned long long pv = ((v >> 32) << 16) | (v & 0xffffULL);
          if (pv < best) { best = pv; bslot = 0x10000 | (int)s; }
        }
      }
#pragma unroll
      for (int mm = 1; mm < 16; mm <<= 1) {
        unsigned long long ob = __shfl_xor(best, mm, 64);
        int obs = __shfl_xor(bslot, mm, 64);
        if (ob < best) { best = ob; bslot = obs; }
      }
      int s = bslot & 0xffff;
      if ((s & 15) == sub) {
        if (bslot & 0x10000) pool[s] = ~0ULL;
        else lst_d[qg * STQ + s] = 0xFFFFFFFFu;   // sentinel > any finite distbits
      }
      if (sub == 0) oq[r] = (unsigned short)(best & 0xffffu);
    }
  }
}

// ======================================================================
// Kernel 2: covariance (sorted order) + eigh -> normals (r9 verbatim)
// ======================================================================
__global__ __launch_bounds__(64) void normals_kernel(const float4* __restrict__ xyz4,
                                                     const unsigned short* __restrict__ nidx,
                                                     float4* __restrict__ nrm4) {
  int gid = blockIdx.x * 64 + threadIdx.x;
  int batch = gid >> 13, q = gid & (N_PTS - 1);
  const float4* __restrict__ xb = xyz4 + batch * N_PTS;
  const float4 qv = xb[q];
  const unsigned short* iq = nidx + (size_t)gid * KNN;
  float c00, c01, c02, c11, c12, c22;
  {
#pragma clang fp contract(off)
    c00 = 0.f; c01 = 0.f; c02 = 0.f; c11 = 0.f; c12 = 0.f; c22 = 0.f;
    for (int j = 0; j < KNN; ++j) {
      float4 pv = xb[iq[j]];
      float dx = pv.x - qv.x, dy = pv.y - qv.y, dz = pv.z - qv.z;
      c00 = c00 + dx * dx; c01 = c01 + dx * dy; c02 = c02 + dx * dz;
      c11 = c11 + dy * dy; c12 = c12 + dy * dz; c22 = c22 + dz * dz;
    }
  }
  float ev[3];
  eigh3_smallest(c00, c01, c02, c11, c12, c22, ev);
  nrm4[gid] = make_float4(ev[0], ev[1], ev[2], 0.0f);
}

// ======================================================================
// Kernel 3: GEMM1 + BN stats (+ optional h store).
// Round 14: 1024 threads = 16 waves/block (was 4) — grid 512 = 2 blk/CU
// was only 8 waves/CU (25%); now 32 waves/CU. Each wave owns 8 output
// channels (acc[8]); per-channel FMA chain order UNCHANGED => h bits
// identical. Stats reduction kept structurally verbatim (t<256, same
// 32-row partials) => stats bits identical.
// ======================================================================
__global__ __launch_bounds__(1024) void gemm1_stats_kernel(const float* __restrict__ x,
                                                           const float4* __restrict__ nrm4,
                                                           const float* __restrict__ w1t,
                                                           const float* __restrict__ b1,
                                                           float* __restrict__ sums,
                                                           float* __restrict__ sumsq,
                                                           float* __restrict__ h) {
  __shared__ float lds[64 * 134];
  const int t = threadIdx.x;
  const int b = blockIdx.x >> 7;
  const int n0 = (blockIdx.x & 127) << 6;
  for (int idx = t; idx < CH * 64; idx += 1024) {
    int cc = idx >> 6, nl = idx & 63;
    lds[nl * 134 + cc] = x[((size_t)(b * CH + cc)) * N_PTS + n0 + nl];
  }
  if (t < 64) {
    float4 nv = nrm4[b * N_PTS + n0 + t];
    lds[t * 134 + 128] = nv.x; lds[t * 134 + 129] = nv.y;
    lds[t * 134 + 130] = nv.z; lds[t * 134 + 131] = 0.0f;
  }
  __syncthreads();

  const int og = __builtin_amdgcn_readfirstlane(t >> 6);   // 0..15
  const int nl = t & 63;
  float acc[8];
#pragma unroll
  for (int k = 0; k < 8; ++k) acc[k] = b1[og * 8 + k];
  for (int c2 = 0; c2 < 66; ++c2) {
    float2 xv = *(const float2*)&lds[nl * 134 + 2 * c2];
    const float* wr0 = w1t + (2 * c2) * CH + og * 8;
    const float* wr1 = wr0 + CH;
#pragma unroll
    for (int k = 0; k < 8; ++k) acc[k] = fmaf(wr0[k], xv.x, acc[k]);
#pragma unroll
    for (int k = 0; k < 8; ++k) acc[k] = fmaf(wr1[k], xv.y, acc[k]);
  }
  if (h != nullptr) {
#pragma unroll
    for (int k = 0; k < 8; ++k) {
      int o = og * 8 + k;
      h[((size_t)(b * CH + o)) * N_PTS + n0 + nl] = acc[k];
    }
  }
  __syncthreads();
#pragma unroll
  for (int k2 = 0; k2 < 4; ++k2)
    *(float2*)&lds[nl * 134 + og * 8 + 2 * k2] = make_float2(acc[2 * k2], acc[2 * k2 + 1]);
  __syncthreads();
  if (t < 256) {
    int cc = t & 127, hf = t >> 7;
    float sm = 0.f, sq = 0.f;
    for (int rr = hf * 32; rr < hf * 32 + 32; ++rr) {
      float v = lds[rr * 134 + cc];
      sm += v; sq = fmaf(v, v, sq);
    }
    atomicAdd(&sums[cc], sm);
    atomicAdd(&sumsq[cc], sq);
  }
}

// ======================================================================
// Kernel 4: finalize BN scale/shift (fallback path only)
// ======================================================================
__global__ void bn_finalize_kernel(const float* __restrict__ sums, const float* __restrict__ sumsq,
                                   const float* __restrict__ gamma, const float* __restrict__ beta,
                                   float* __restrict__ scale, float* __restrict__ shift) {
  int c = threadIdx.x;
  if (c < CH) {
    const double cnt = (double)(BATCH * N_PTS);
    double mean = (double)sums[c] / cnt;
    double var = (double)sumsq[c] / cnt - mean * mean;
    double inv = 1.0 / sqrt(var + 1e-5);
    double sc = (double)gamma[c] * inv;
    scale[c] = (float)sc;
    shift[c] = (float)((double)beta[c] - mean * sc);
  }
}

// ======================================================================
// Kernel 5 (primary): BN(inline scale/shift) + ReLU + GEMM2 from stored h.
// Round 14: 1024 threads = 16 waves (was 4) for 32 waves/CU; each wave 8
// channels. Per-channel GEMM2 chain order unchanged => bit-identical.
// ======================================================================
__global__ __launch_bounds__(1024) void bn_out_kernel(const float* __restrict__ h,
                                                      const float* __restrict__ w2t,
                                                      const float* __restrict__ b2,
                                                      const float* __restrict__ sums,
                                                      const float* __restrict__ sumsq,
                                                      const float* __restrict__ gamma,
                                                      const float* __restrict__ beta,
                                                      float* __restrict__ out) {
  __shared__ float lds[64 * 134];
  __shared__ float s_scale[CH];
  __shared__ float s_shift[CH];
  const int t = threadIdx.x;
  const int b = blockIdx.x >> 7;
  const int n0 = (blockIdx.x & 127) << 6;
  if (t < CH) {
    const double cnt = (double)(BATCH * N_PTS);
    double mean = (double)sums[t] / cnt;
    double var = (double)sumsq[t] / cnt - mean * mean;
    double inv = 1.0 / sqrt(var + 1e-5);
    double sc = (double)gamma[t] * inv;
    s_scale[t] = (float)sc;
    s_shift[t] = (float)((double)beta[t] - mean * sc);
  }
  for (int idx = t; idx < CH * 64; idx += 1024) {
    int cc = idx >> 6, nl = idx & 63;
    lds[nl * 134 + cc] = h[((size_t)(b * CH + cc)) * N_PTS + n0 + nl];
  }
  __syncthreads();
  // apply BN + ReLU in LDS (same formula/values as fused_out's register path)
  for (int idx = t; idx < CH * 64; idx += 1024) {
    int cc = idx >> 6, nl = idx & 63;
    float v = lds[nl * 134 + cc];
    lds[nl * 134 + cc] = fmaxf(fmaf(v, s_scale[cc], s_shift[cc]), 0.0f);
  }
  __syncthreads();

  const int og = __builtin_amdgcn_readfirstlane(t >> 6);   // 0..15
  const int nl = t & 63;
  float acc2[8];
#pragma unroll
  for (int k = 0; k < 8; ++k) acc2[k] = b2[og * 8 + k];
  for (int c2 = 0; c2 < 64; ++c2) {
    float2 hv = *(const float2*)&lds[nl * 134 + 2 * c2];
    const float* wr0 = w2t + (2 * c2) * CH + og * 8;
    const float* wr1 = wr0 + CH;
#pragma unroll
    for (int k = 0; k < 8; ++k) acc2[k] = fmaf(wr0[k], hv.x, acc2[k]);
#pragma unroll
    for (int k = 0; k < 8; ++k) acc2[k] = fmaf(wr1[k], hv.y, acc2[k]);
  }
#pragma unroll
  for (int k = 0; k < 8; ++k) {
    int o = og * 8 + k;
    out[((size_t)(b * CH + o)) * N_PTS + n0 + nl] = acc2[k];
  }
}

// ======================================================================
// Kernel 5b (fallback, ws too small): original fused GEMM1+BN+ReLU+GEMM2
// ======================================================================
__global__ __launch_bounds__(256) void fused_out_kernel(const float* __restrict__ x,
                                                        const float4* __restrict__ nrm4,
                                                        const float* __restrict__ w1t,
                                                        const float* __restrict__ b1,
                                                        const float* __restrict__ w2t,
                                                        const float* __restrict__ b2,
                                                        const float* __restrict__ scale,
                                                        const float* __restrict__ shift,
                                                        float* __restrict__ out) {
  __shared__ float lds[64 * 134];
  const int t = threadIdx.x;
  const int b = blockIdx.x >> 7;
  const int n0 = (blockIdx.x & 127) << 6;
  for (int idx = t; idx < CH * 64; idx += 256) {
    int cc = idx >> 6, nl = idx & 63;
    lds[nl * 134 + cc] = x[((size_t)(b * CH + cc)) * N_PTS + n0 + nl];
  }
  if (t < 64) {
    float4 nv = nrm4[b * N_PTS + n0 + t];
    lds[t * 134 + 128] = nv.x; lds[t * 134 + 129] = nv.y;
    lds[t * 134 + 130] = nv.z; lds[t * 134 + 131] = 0.0f;
  }
  __syncthreads();

  const int og = __builtin_amdgcn_readfirstlane(t >> 6);
  const int nl = t & 63;
  float acc[32];
#pragma unroll
  for (int k = 0; k < 32; ++k) acc[k] = b1[og * 32 + k];
  for (int c2 = 0; c2 < 66; ++c2) {
    float2 xv = *(const float2*)&lds[nl * 134 + 2 * c2];
    const float* wr0 = w1t + (2 * c2) * CH + og * 32;
    const float* wr1 = wr0 + CH;
#pragma unroll
    for (int k = 0; k < 32; ++k) acc[k] = fmaf(wr0[k], xv.x, acc[k]);
#pragma unroll
    for (int k = 0; k < 32; ++k) acc[k] = fmaf(wr1[k], xv.y, acc[k]);
  }
#pragma unroll
  for (int k = 0; k < 32; ++k) {
    float sc = scale[og * 32 + k], sh = shift[og * 32 + k];
    acc[k] = fmaxf(fmaf(acc[k], sc, sh), 0.0f);
  }
  __syncthreads();
#pragma unroll
  for (int k2 = 0; k2 < 16; ++k2)
    *(float2*)&lds[nl * 134 + og * 32 + 2 * k2] = make_float2(acc[2 * k2], acc[2 * k2 + 1]);
  __syncthreads();

  float acc2[32];
#pragma unroll
  for (int k = 0; k < 32; ++k) acc2[k] = b2[og * 32 + k];
  for (int c2 = 0; c2 < 64; ++c2) {
    float2 hv = *(const float2*)&lds[nl * 134 + 2 * c2];
    const float* wr0 = w2t + (2 * c2) * CH + og * 32;
    const float* wr1 = wr0 + CH;
#pragma unroll
    for (int k = 0; k < 32; ++k) acc2[k] = fmaf(wr0[k], hv.x, acc2[k]);
#pragma unroll
    for (int k = 0; k < 32; ++k) acc2[k] = fmaf(wr1[k], hv.y, acc2[k]);
  }
#pragma unroll
  for (int k = 0; k < 32; ++k) {
    int o = og * 32 + k;
    out[((size_t)(b * CH + o)) * N_PTS + n0 + nl] = acc2[k];
  }
}

// ======================================================================
extern "C" void kernel_launch(void* const* d_in, const int* in_sizes, int n_in,
                              void* d_out, int out_size, void* d_ws, size_t ws_size,
                              hipStream_t stream) {
  const float* x     = (const float*)d_in[0];
  const float* xyz   = (const float*)d_in[1];
  const float* w1    = (const float*)d_in[2];
  const float* b1    = (const float*)d_in[3];
  const float* gamma = (const float*)d_in[4];
  const float* beta  = (const float*)d_in[5];
  const float* w2    = (const float*)d_in[6];
  const float* b2    = (const float*)d_in[7];
  float* out = (float*)d_out;

  float* W = (float*)d_ws;
  float4* xyz4 = (float4*)W;                         // floats [0, 131072)
  float4* nrm4 = (float4*)(W + 131072);              // floats [131072, 262144)
  float* w1t   = W + 262144;                         // [262144, 279040)
  float* w2t   = W + 279040;                         // [279040, 295424)
  float* stats = W + 295424;                         // [295424, 295680)
  float* scale = W + 295680;                         // [295680, 295808)
  float* shift = W + 295808;                         // [295808, 295936)
  unsigned short* nidx = (unsigned short*)(W + 295936);  // 32768*20 u16 = 327680 floats -> ends 623616
  float* h     = W + 624640;                         // 4*128*8192 floats = 16.78 MB (16B-aligned)

  const size_t need = (size_t)(624640 + (size_t)BATCH * CH * N_PTS) * 4;
  const bool use_h = (ws_size >= need);

  prep_kernel<<<128, 256, 0, stream>>>(xyz, w1, w2, xyz4, w1t, w2t, stats);
  knn_select_kernel<<<BATCH * N_PTS / 64, 1024, 0, stream>>>(xyz4, nidx);
  normals_kernel<<<BATCH * N_PTS / 64, 64, 0, stream>>>(xyz4, nidx, nrm4);
  gemm1_stats_kernel<<<BATCH * N_PTS / 64, 1024, 0, stream>>>(x, nrm4, w1t, b1, stats, stats + 128,
                                                              use_h ? h : nullptr);
  if (use_h) {
    bn_out_kernel<<<BATCH * N_PTS / 64, 1024, 0, stream>>>(h, w2t, b2, stats, stats + 128,
                                                           gamma, beta, out);
  } else {
    bn_finalize_kernel<<<1, 128, 0, stream>>>(stats, stats + 128, gamma, beta, scale, shift);
    fused_out_kernel<<<BATCH * N_PTS / 64, 256, 0, stream>>>(x, nrm4, w1t, b1, w2t, b2, scale, shift, out);
  }
}

// Round 15
// 327.647 us; speedup vs baseline: 1.1572x; 1.0222x over previous
//
#include <hip/hip_runtime.h>
#include <math.h>

#define N_PTS 8192
#define BATCH 4
#define CH 128
#define KNN 20
#define CAP 112
#define STQ 114
#define POOL 256

// ======================================================================
// LAPACK ssyevd emulation for 3x3 symmetric (lower), SINGLE precision,
// matching numpy's float32 eigh path bit-for-bit where decisions matter.
// (verified passing — do not perturb numerics)
// ======================================================================

__device__ __forceinline__ float slapy2f(float x, float y) {
#pragma clang fp contract(off)
  float ax = fabsf(x), ay = fabsf(y);
  float w = fmaxf(ax, ay), z = fminf(ax, ay);
  if (z == 0.0f) return w;
  float t = z / w;
  return w * sqrtf(1.0f + t * t);
}

__device__ __forceinline__ void slartgf(float f, float g, float* cs, float* sn, float* r) {
#pragma clang fp contract(off)
  if (g == 0.0f) { *cs = 1.0f; *sn = 0.0f; *r = f; }
  else if (f == 0.0f) { *cs = 0.0f; *sn = copysignf(1.0f, g); *r = fabsf(g); }
  else {
    float f1 = fabsf(f);
    float d = sqrtf(f * f + g * g);
    *cs = f1 / d;
    *r = copysignf(d, f);
    *sn = g / (*r);
  }
}

__device__ void slaev2f(float a, float b, float c, float* rt1, float* rt2,
                        float* cs1, float* sn1) {
#pragma clang fp contract(off)
  float sm = a + c, df = a - c, adf = fabsf(df);
  float tb = b + b, ab = fabsf(tb);
  float acmx, acmn;
  if (fabsf(a) > fabsf(c)) { acmx = a; acmn = c; } else { acmx = c; acmn = a; }
  float rt;
  if (adf > ab)      { float q = ab / adf;  rt = adf * sqrtf(1.0f + q * q); }
  else if (adf < ab) { float q = adf / ab;  rt = ab * sqrtf(1.0f + q * q); }
  else               rt = ab * sqrtf(2.0f);
  int sgn1;
  if (sm < 0.0f)      { *rt1 = 0.5f * (sm - rt); sgn1 = -1; *rt2 = (acmx / *rt1) * acmn - (b / *rt1) * b; }
  else if (sm > 0.0f) { *rt1 = 0.5f * (sm + rt); sgn1 = 1;  *rt2 = (acmx / *rt1) * acmn - (b / *rt1) * b; }
  else                { *rt1 = 0.5f * rt; *rt2 = -0.5f * rt; sgn1 = 1; }
  float cs; int sgn2;
  if (df >= 0.0f) { cs = df + rt; sgn2 = 1; } else { cs = df - rt; sgn2 = -1; }
  float acs = fabsf(cs);
  if (acs > ab) {
    float ct = -tb / cs;
    *sn1 = 1.0f / sqrtf(1.0f + ct * ct);
    *cs1 = ct * (*sn1);
  } else {
    if (ab == 0.0f) { *cs1 = 1.0f; *sn1 = 0.0f; }
    else {
      float tn = -cs / tb;
      *cs1 = 1.0f / sqrtf(1.0f + tn * tn);
      *sn1 = tn * (*cs1);
    }
  }
  if (sgn1 == sgn2) { float tn = *cs1; *cs1 = -(*sn1); *sn1 = tn; }
}

__device__ void eigh3_smallest(float a00, float a10, float a20,
                               float a11, float a21, float a22, float evec[3]) {
#pragma clang fp contract(off)
  float d[3], e[2], tau = 0.0f, v2 = 0.0f;
  d[0] = a00;
  {
    float xnorm = sqrtf(a20 * a20);   // snrm2(1)
    if (xnorm == 0.0f) {
      tau = 0.0f; v2 = 0.0f;
      e[0] = a10; d[1] = a11; e[1] = a21; d[2] = a22;
    } else {
      float alpha = a10;
      float beta = -copysignf(slapy2f(alpha, xnorm), alpha);
      tau = (beta - alpha) / beta;
      float invs = 1.0f / (alpha - beta);
      v2 = a20 * invs;
      e[0] = beta;
      float y0 = tau * a11;
      float y1 = tau * a21;
      y0 = y0 + tau * (a21 * v2);
      y1 = y1 + (tau * v2) * a22;
      float dot = y0 + y1 * v2;
      float al = (-0.5f * tau) * dot;
      float w0 = y0 + al;
      float w1 = y1 + al * v2;
      a11 = (a11 - w0) - w0;
      a21 = (a21 - v2 * w0) - w1;
      a22 = (a22 - v2 * w1) - w1 * v2;
      d[1] = a11; e[1] = a21; d[2] = a22;
    }
  }

  float z[3][3] = {{1.0f,0.0f,0.0f},{0.0f,1.0f,0.0f},{0.0f,0.0f,1.0f}};
  const float eps = 5.9604644775390625e-08f;
  const float eps2 = 3.5527136788005009e-15f;
  const float safmin = 1.1754943508222875e-38f;
  int nmaxit = 90, jtot = 0;
  int l1 = 0;
  int l, m, lend, lsv, lendsv;
  float p, g, r, c, s, f, b_, rt1, rt2, tst;
  float wc[2], wsn[2];

outer_loop:
  if (l1 > 2) goto sorting;
  if (l1 > 0) e[l1 - 1] = 0.0f;
  {
    int mm;
    for (mm = l1; mm <= 1; ++mm) {
      tst = fabsf(e[mm]);
      if (tst == 0.0f) break;
      if (tst <= (sqrtf(fabsf(d[mm])) * sqrtf(fabsf(d[mm + 1]))) * eps) { e[mm] = 0.0f; break; }
    }
    m = (mm > 1) ? 2 : mm;
  }
  l = l1; lsv = l; lend = m; lendsv = lend; l1 = m + 1;
  if (lend == l) goto outer_loop;
  {
    float an = 0.0f;
    for (int i2 = l; i2 <= lend; ++i2) an = fmaxf(an, fabsf(d[i2]));
    for (int i2 = l; i2 < lend; ++i2) an = fmaxf(an, fabsf(e[i2]));
    if (an == 0.0f) goto outer_loop;
  }
  if (fabsf(d[lend]) < fabsf(d[l])) { lend = lsv; l = lendsv; }

  if (lend > l) {
ql40:
    if (l != lend) {
      for (m = l; m <= lend - 1; ++m) {
        tst = e[m] * e[m];
        if (tst <= (eps2 * fabsf(d[m])) * fabsf(d[m + 1]) + safmin) goto ql60;
      }
    }
    m = lend;
ql60:
    if (m < lend) e[m] = 0.0f;
    p = d[l];
    if (m == l) goto ql80;
    if (m == l + 1) {
      slaev2f(d[l], e[l], d[l + 1], &rt1, &rt2, &c, &s);
      for (int i2 = 0; i2 < 3; ++i2) {
        float temp = z[i2][l + 1];
        z[i2][l + 1] = c * temp - s * z[i2][l];
        z[i2][l]     = s * temp + c * z[i2][l];
      }
      d[l] = rt1; d[l + 1] = rt2; e[l] = 0.0f;
      l += 2;
      if (l <= lend) goto ql40;
      goto done140;
    }
    if (jtot == nmaxit) goto done140;
    jtot++;
    g = (d[l + 1] - p) / (2.0f * e[l]);
    r = slapy2f(g, 1.0f);
    g = d[m] - p + e[l] / (g + copysignf(r, g));
    s = 1.0f; c = 1.0f; p = 0.0f;
    for (int i2 = m - 1; i2 >= l; --i2) {
      f = s * e[i2]; b_ = c * e[i2];
      slartgf(g, f, &c, &s, &r);
      if (i2 != m - 1) e[i2 + 1] = r;
      g = d[i2 + 1] - p;
      r = (d[i2] - g) * s + 2.0f * c * b_;
      p = s * r;
      d[i2 + 1] = g + p;
      g = c * r - b_;
      wc[i2] = c; wsn[i2] = -s;
    }
    for (int j = m - 1; j >= l; --j) {
      float ct = wc[j], st = wsn[j];
      for (int i2 = 0; i2 < 3; ++i2) {
        float temp = z[i2][j + 1];
        z[i2][j + 1] = ct * temp - st * z[i2][j];
        z[i2][j]     = st * temp + ct * z[i2][j];
      }
    }
    d[l] -= p;
    e[l] = g;
    goto ql40;
ql80:
    d[l] = p;
    l += 1;
    if (l <= lend) goto ql40;
    goto done140;
  } else {
qr90:
    if (l != lend) {
      for (m = l; m >= lend + 1; --m) {
        tst = e[m - 1] * e[m - 1];
        if (tst <= (eps2 * fabsf(d[m])) * fabsf(d[m - 1]) + safmin) goto qr110;
      }
    }
    m = lend;
qr110:
    if (m > lend) e[m - 1] = 0.0f;
    p = d[l];
    if (m == l) goto qr130;
    if (m == l - 1) {
      slaev2f(d[l - 1], e[l - 1], d[l], &rt1, &rt2, &c, &s);
      for (int i2 = 0; i2 < 3; ++i2) {
        float temp = z[i2][l];
        z[i2][l]     = c * temp - s * z[i2][l - 1];
        z[i2][l - 1] = s * temp + c * z[i2][l - 1];
      }
      d[l - 1] = rt1; d[l] = rt2; e[l - 1] = 0.0f;
      l -= 2;
      if (l >= lend) goto qr90;
      goto done140;
    }
    if (jtot == nmaxit) goto done140;
    jtot++;
    g = (d[l - 1] - p) / (2.0f * e[l - 1]);
    r = slapy2f(g, 1.0f);
    g = d[m] - p + e[l - 1] / (g + copysignf(r, g));
    s = 1.0f; c = 1.0f; p = 0.0f;
    for (int i2 = m; i2 <= l - 1; ++i2) {
      f = s * e[i2]; b_ = c * e[i2];
      slartgf(g, f, &c, &s, &r);
      if (i2 != m) e[i2 - 1] = r;
      g = d[i2] - p;
      r = (d[i2 + 1] - g) * s + 2.0f * c * b_;
      p = s * r;
      d[i2] = g + p;
      g = c * r - b_;
      wc[i2] = c; wsn[i2] = s;
    }
    for (int j = m; j <= l - 1; ++j) {
      float ct = wc[j], st = wsn[j];
      for (int i2 = 0; i2 < 3; ++i2) {
        float temp = z[i2][j + 1];
        z[i2][j + 1] = ct * temp - st * z[i2][j];
        z[i2][j]     = st * temp + ct * z[i2][j];
      }
    }
    d[l] -= p;
    e[l - 1] = g;
    goto qr90;
qr130:
    d[l] = p;
    l -= 1;
    if (l >= lend) goto qr90;
    goto done140;
  }
done140:
  if (jtot < nmaxit) goto outer_loop;
sorting:
  for (int ii = 1; ii <= 2; ++ii) {
    int i_ = ii - 1, k = i_;
    p = d[i_];
    for (int j = ii; j <= 2; ++j) if (d[j] < p) { k = j; p = d[j]; }
    if (k != i_) {
      d[k] = d[i_]; d[i_] = p;
      for (int i2 = 0; i2 < 3; ++i2) { float tz = z[i2][i_]; z[i2][i_] = z[i2][k]; z[i2][k] = tz; }
    }
  }
  {
    float z10 = z[1][0], z20 = z[2][0];
    float sum = z10 + v2 * z20;
    evec[0] = z[0][0];
    evec[1] = z10 - tau * sum;
    evec[2] = z20 - tau * sum * v2;
  }
}

// ======================================================================
// Kernel 0: prep
// xyz4.w holds -0.5*|p|^2 (EXACT: power-of-2 scale). |p|^2 recoverable
// bit-exactly as -2*w => exact-distance formula downstream bit-identical.
// ======================================================================
__global__ __launch_bounds__(256) void prep_kernel(const float* __restrict__ xyz,
                                                   const float* __restrict__ w1,
                                                   const float* __restrict__ w2,
                                                   float4* __restrict__ xyz4,
                                                   float* __restrict__ w1t,
                                                   float* __restrict__ w2t,
                                                   float* __restrict__ stats) {
  int idx = blockIdx.x * 256 + threadIdx.x;
  if (idx < BATCH * N_PTS) {
    float x = xyz[idx * 3], y = xyz[idx * 3 + 1], zz = xyz[idx * 3 + 2];
    float sq = fmaf(zz, zz, fmaf(y, y, x * x));
    xyz4[idx] = make_float4(x, y, zz, -0.5f * sq);
  }
  if (idx < 132 * CH) {
    int cc = idx >> 7, o = idx & 127;
    w1t[idx] = (cc < 131) ? w1[o * 131 + cc] : 0.0f;
  }
  if (idx < CH * CH) {
    int cc = idx >> 7, o = idx & 127;
    w2t[idx] = w2[o * CH + cc];
  }
  if (idx < 256) stats[idx] = 0.0f;
}

// exact dist, bit-identical to original qdist (w fields hold -0.5*sq)
__device__ __forceinline__ float qdist2(const float4 qv, const float4 cv) {
  float dot = fmaf(qv.x, cv.x, fmaf(qv.y, cv.y, qv.z * cv.z));
  return fmaf(-2.0f, dot, (-2.0f * qv.w) + (-2.0f * cv.w));
}

__device__ __forceinline__ unsigned int distbits(float dist) {
  unsigned int du = __float_as_uint(dist);
  return (du & 0x80000000u) ? ~du : (du | 0x80000000u);  // monotone total order
}

// ======================================================================
// Kernel 1: exact 20-NN — r9 structure + exact per-wave TOP-3 (round 15).
//  r9's top-2-of-wave bound degrades when a group's true top-3 lands 3-0
//  in one half (P=1/4/group) => looser Tq => more P2 collect entries and
//  longer P3 scans. Restore r8's exact 5-op top-3 network (kept inside
//  r9's copy-free dual buffers); group bound = EXACT group-3rd via
//  3rd(U) = max(max(a2,b2), max(min(a1,b0), min(a0,b1))) (r8-verified).
//  Certification unchanged: >=3/group x 8 groups => Tq >= d20; slack
//  covers cheap-vs-exact fp32 discrepancy; selection threshold-
//  independent => bit-identical output.
// ======================================================================
__global__ __launch_bounds__(1024, 8) void knn_select_kernel(const float4* __restrict__ xyz4,
                                                             unsigned short* __restrict__ nidx) {
  __shared__ unsigned int lst_d[64 * STQ];      // 29184 B
  __shared__ unsigned short lst_i[64 * STQ];    // 14592 B
  __shared__ float bnd[16 * 64 * 3];            // 12288 B (top-3 per wave,lane)
  __shared__ unsigned long long pool[POOL];     // 2048 B
  __shared__ unsigned int qcnt[64];
  __shared__ unsigned int qflag[64];
  __shared__ unsigned int qover[64];
  __shared__ unsigned int pool_cnt;

  const int t = threadIdx.x;
  const int w = t >> 6, l = t & 63;
  const int batch = blockIdx.x >> 7;               // 128 blocks per batch
  const int q0 = (blockIdx.x & 127) << 6;          // 64 queries per block
  const float4* __restrict__ xb = xyz4 + batch * N_PTS;
  const float4 qv = xb[q0 + l];
  const float qw = -2.0f * qv.w;                   // exact |q|^2

  if (t < 64) { qcnt[t] = 0; qflag[t] = 0; qover[t] = 0; }
  if (t == 0) pool_cnt = 0;

  const int base = __builtin_amdgcn_readfirstlane(w * 512);

#define KF(cv) fmaf(qv.x, (cv).x, fmaf(qv.y, (cv).y, fmaf(qv.z, (cv).z, (cv).w)))

  // ---- P1: exact top-3-largest k over this wave's 512 pts (dual buffer) ----
  float a0 = -INFINITY, a1 = -INFINITY, a2 = -INFINITY;
  {
    float4 pA0 = xb[base + 0], pA1 = xb[base + 1], pA2 = xb[base + 2], pA3 = xb[base + 3];
    float4 pB0 = xb[base + 4], pB1 = xb[base + 5], pB2 = xb[base + 6], pB3 = xb[base + 7];
#define TOP3(kk) { float t0 = fminf(a0, kk); a0 = fmaxf(a0, kk); \
                   float t1 = fminf(a1, t0); a1 = fmaxf(a1, t0); \
                   a2 = fmaxf(a2, t1); }
    for (int i = 0; i < 512; i += 8) {
      float k0 = KF(pA0); pA0 = xb[base + i + 8];
      float k1 = KF(pA1); pA1 = xb[base + i + 9];
      float k2 = KF(pA2); pA2 = xb[base + i + 10];
      float k3 = KF(pA3); pA3 = xb[base + i + 11];
      TOP3(k0) TOP3(k1) TOP3(k2) TOP3(k3)
      k0 = KF(pB0); pB0 = xb[base + i + 12];
      k1 = KF(pB1); pB1 = xb[base + i + 13];
      k2 = KF(pB2); pB2 = xb[base + i + 14];
      k3 = KF(pB3); pB3 = xb[base + i + 15];
      TOP3(k0) TOP3(k1) TOP3(k2) TOP3(k3)
    }
#undef TOP3
  }
  {
    int bi = (w * 64 + l) * 3;
    bnd[bi] = a0; bnd[bi + 1] = a1; bnd[bi + 2] = a2;
  }
  __syncthreads();

  // per-1024-group EXACT 3rd-largest via wave-pair top-3 merge (r8 formula)
  float kmin = INFINITY;
#pragma unroll
  for (int g = 0; g < 8; ++g) {
    int ai = ((2 * g) * 64 + l) * 3;
    int bi = ((2 * g + 1) * 64 + l) * 3;
    float pa0 = bnd[ai], pa1 = bnd[ai + 1], pa2 = bnd[ai + 2];
    float pb0 = bnd[bi], pb1 = bnd[bi + 1], pb2 = bnd[bi + 2];
    float third = fmaxf(fmaxf(pa2, pb2), fmaxf(fminf(pa1, pb0), fminf(pa0, pb1)));
    kmin = fminf(kmin, third);
  }
  float Tq = fmaf(-2.0f, kmin, qw);
  Tq = Tq + (fabsf(Tq) * 2e-5f + 1e-3f);           // rounding slack (>>3e-5 worst case)
  const float thK = 0.5f * (qw - Tq) - 1e-3f;      // prefilter: k>=thK <=> dist_k<=Tq+2e-3

  // ---- P2: collect (dual buffer + 3-fma prefilter) ----
  {
    float4 pA0 = xb[base + 0], pA1 = xb[base + 1], pA2 = xb[base + 2], pA3 = xb[base + 3];
    float4 pB0 = xb[base + 4], pB1 = xb[base + 5], pB2 = xb[base + 6], pB3 = xb[base + 7];
#define COLLECT(cv, idx_) {                                                     \
      float k = KF(cv);                                                         \
      if (k >= thK) {                                                           \
        float dot = fmaf(qv.x, (cv).x, fmaf(qv.y, (cv).y, qv.z * (cv).z));      \
        float dist = fmaf(-2.0f, dot, qw + (-2.0f * (cv).w));                   \
        if (dist <= Tq) {                                                       \
          unsigned int db = distbits(dist);                                     \
          unsigned int pos = atomicAdd(&qcnt[l], 1u);                           \
          if (pos < CAP) {                                                      \
            lst_d[l * STQ + pos] = db;                                          \
            lst_i[l * STQ + pos] = (unsigned short)(idx_);                      \
          } else {                                                              \
            unsigned long long key = ((unsigned long long)db << 32)             \
                                   | ((unsigned int)l << 16) | (unsigned int)(idx_); \
            unsigned int pp = atomicAdd(&pool_cnt, 1u);                         \
            if (pp < POOL) { pool[pp] = key; qflag[l] = 1u; }                   \
            else qover[l] = 1u;                                                 \
          }                                                                     \
        }                                                                       \
      }                                                                         \
    }
    for (int i = 0; i < 512; i += 8) {
      float4 cA0 = pA0; pA0 = xb[base + i + 8];
      float4 cA1 = pA1; pA1 = xb[base + i + 9];
      float4 cA2 = pA2; pA2 = xb[base + i + 10];
      float4 cA3 = pA3; pA3 = xb[base + i + 11];
      COLLECT(cA0, base + i)     COLLECT(cA1, base + i + 1)
      COLLECT(cA2, base + i + 2) COLLECT(cA3, base + i + 3)
      float4 cB0 = pB0; pB0 = xb[base + i + 12];
      float4 cB1 = pB1; pB1 = xb[base + i + 13];
      float4 cB2 = pB2; pB2 = xb[base + i + 14];
      float4 cB3 = pB3; pB3 = xb[base + i + 15];
      COLLECT(cB0, base + i + 4) COLLECT(cB1, base + i + 5)
      COLLECT(cB2, base + i + 6) COLLECT(cB3, base + i + 7)
    }
#undef COLLECT
  }
#undef KF
  __syncthreads();

  // ---- P3: parallel top-20 (16 lanes per query, 64 queries) ----
  const int qg = t >> 4, sub = t & 15;
  unsigned int n = qcnt[qg]; if (n > CAP) n = CAP;
  const unsigned int pcnt = (qflag[qg] && !qover[qg]) ? min(pool_cnt, (unsigned int)POOL) : 0u;
  unsigned short* oq = nidx + ((size_t)(batch * N_PTS + q0 + qg)) * KNN;

  if (qover[qg]) {
    if (sub == 0) {
      // exact serial fallback (astronomically rare)
      unsigned long long best[KNN];
#pragma unroll
      for (int j = 0; j < KNN; ++j) best[j] = ~0ULL;
      const float4 qv2 = xb[q0 + qg];
      for (int m = 0; m < N_PTS; ++m) {
        float dist = qdist2(qv2, xb[m]);
        unsigned long long p = ((unsigned long long)distbits(dist) << 32) | (unsigned int)m;
        if (p < best[KNN - 1]) {
          int j = KNN - 1;
          while (j > 0 && best[j - 1] > p) { best[j] = best[j - 1]; --j; }
          best[j] = p;
        }
      }
      for (int j = 0; j < KNN; ++j) oq[j] = (unsigned short)(best[j] & 0xffffu);
    }
  } else {
    for (int r = 0; r < KNN; ++r) {
      unsigned long long best = ~0ULL; int bslot = 0;
      for (unsigned int s = sub; s < n; s += 16) {
        unsigned long long v = ((unsigned long long)lst_d[qg * STQ + s] << 16)
                             | (unsigned long long)lst_i[qg * STQ + s];
        if (v < best) { best = v; bslot = (int)s; }
      }
      for (unsigned int s = sub; s < pcnt; s += 16) {
        unsigned long long v = pool[s];
        if ((unsigned int)((v >> 16) & 0xffffu) == (unsigned int)qg) {
          unsigned long long pv = ((v >> 32) << 16) | (v & 0xffffULL);
          if (pv < best) { best = pv; bslot = 0x10000 | (int)s; }
        }
      }
#pragma unroll
      for (int mm = 1; mm < 16; mm <<= 1) {
        unsigned long long ob = __shfl_xor(best, mm, 64);
        int obs = __shfl_xor(bslot, mm, 64);
        if (ob < best) { best = ob; bslot = obs; }
      }
      int s = bslot & 0xffff;
      if ((s & 15) == sub) {
        if (bslot & 0x10000) pool[s] = ~0ULL;
        else lst_d[qg * STQ + s] = 0xFFFFFFFFu;   // sentinel > any finite distbits
      }
      if (sub == 0) oq[r] = (unsigned short)(best & 0xffffu);
    }
  }
}

// ======================================================================
// Kernel 2: covariance (sorted order) + eigh -> normals (r9 verbatim)
// ======================================================================
__global__ __launch_bounds__(64) void normals_kernel(const float4* __restrict__ xyz4,
                                                     const unsigned short* __restrict__ nidx,
                                                     float4* __restrict__ nrm4) {
  int gid = blockIdx.x * 64 + threadIdx.x;
  int batch = gid >> 13, q = gid & (N_PTS - 1);
  const float4* __restrict__ xb = xyz4 + batch * N_PTS;
  const float4 qv = xb[q];
  const unsigned short* iq = nidx + (size_t)gid * KNN;
  float c00, c01, c02, c11, c12, c22;
  {
#pragma clang fp contract(off)
    c00 = 0.f; c01 = 0.f; c02 = 0.f; c11 = 0.f; c12 = 0.f; c22 = 0.f;
    for (int j = 0; j < KNN; ++j) {
      float4 pv = xb[iq[j]];
      float dx = pv.x - qv.x, dy = pv.y - qv.y, dz = pv.z - qv.z;
      c00 = c00 + dx * dx; c01 = c01 + dx * dy; c02 = c02 + dx * dz;
      c11 = c11 + dy * dy; c12 = c12 + dy * dz; c22 = c22 + dz * dz;
    }
  }
  float ev[3];
  eigh3_smallest(c00, c01, c02, c11, c12, c22, ev);
  nrm4[gid] = make_float4(ev[0], ev[1], ev[2], 0.0f);
}

// ======================================================================
// Kernel 3: GEMM1 + BN stats (+ optional h store). r14 structure:
// 1024 thr = 16 waves (32 waves/CU); wave owns 8 channels; per-channel
// FMA chain order unchanged => h bits identical; stats reduction
// structurally verbatim (t<256) => stats bits identical.
// ======================================================================
__global__ __launch_bounds__(1024) void gemm1_stats_kernel(const float* __restrict__ x,
                                                           const float4* __restrict__ nrm4,
                                                           const float* __restrict__ w1t,
                                                           const float* __restrict__ b1,
                                                           float* __restrict__ sums,
                                                           float* __restrict__ sumsq,
                                                           float* __restrict__ h) {
  __shared__ float lds[64 * 134];
  const int t = threadIdx.x;
  const int b = blockIdx.x >> 7;
  const int n0 = (blockIdx.x & 127) << 6;
  for (int idx = t; idx < CH * 64; idx += 1024) {
    int cc = idx >> 6, nl = idx & 63;
    lds[nl * 134 + cc] = x[((size_t)(b * CH + cc)) * N_PTS + n0 + nl];
  }
  if (t < 64) {
    float4 nv = nrm4[b * N_PTS + n0 + t];
    lds[t * 134 + 128] = nv.x; lds[t * 134 + 129] = nv.y;
    lds[t * 134 + 130] = nv.z; lds[t * 134 + 131] = 0.0f;
  }
  __syncthreads();

  const int og = __builtin_amdgcn_readfirstlane(t >> 6);   // 0..15
  const int nl = t & 63;
  float acc[8];
#pragma unroll
  for (int k = 0; k < 8; ++k) acc[k] = b1[og * 8 + k];
  for (int c2 = 0; c2 < 66; ++c2) {
    float2 xv = *(const float2*)&lds[nl * 134 + 2 * c2];
    const float* wr0 = w1t + (2 * c2) * CH + og * 8;
    const float* wr1 = wr0 + CH;
#pragma unroll
    for (int k = 0; k < 8; ++k) acc[k] = fmaf(wr0[k], xv.x, acc[k]);
#pragma unroll
    for (int k = 0; k < 8; ++k) acc[k] = fmaf(wr1[k], xv.y, acc[k]);
  }
  if (h != nullptr) {
#pragma unroll
    for (int k = 0; k < 8; ++k) {
      int o = og * 8 + k;
      h[((size_t)(b * CH + o)) * N_PTS + n0 + nl] = acc[k];
    }
  }
  __syncthreads();
#pragma unroll
  for (int k2 = 0; k2 < 4; ++k2)
    *(float2*)&lds[nl * 134 + og * 8 + 2 * k2] = make_float2(acc[2 * k2], acc[2 * k2 + 1]);
  __syncthreads();
  if (t < 256) {
    int cc = t & 127, hf = t >> 7;
    float sm = 0.f, sq = 0.f;
    for (int rr = hf * 32; rr < hf * 32 + 32; ++rr) {
      float v = lds[rr * 134 + cc];
      sm += v; sq = fmaf(v, v, sq);
    }
    atomicAdd(&sums[cc], sm);
    atomicAdd(&sumsq[cc], sq);
  }
}

// ======================================================================
// Kernel 4: finalize BN scale/shift (fallback path only)
// ======================================================================
__global__ void bn_finalize_kernel(const float* __restrict__ sums, const float* __restrict__ sumsq,
                                   const float* __restrict__ gamma, const float* __restrict__ beta,
                                   float* __restrict__ scale, float* __restrict__ shift) {
  int c = threadIdx.x;
  if (c < CH) {
    const double cnt = (double)(BATCH * N_PTS);
    double mean = (double)sums[c] / cnt;
    double var = (double)sumsq[c] / cnt - mean * mean;
    double inv = 1.0 / sqrt(var + 1e-5);
    double sc = (double)gamma[c] * inv;
    scale[c] = (float)sc;
    shift[c] = (float)((double)beta[c] - mean * sc);
  }
}

// ======================================================================
// Kernel 5 (primary): BN(inline scale/shift) + ReLU + GEMM2 from stored h.
// r14 structure: 1024 thr = 16 waves; wave owns 8 channels; chain order
// unchanged => bit-identical.
// ======================================================================
__global__ __launch_bounds__(1024) void bn_out_kernel(const float* __restrict__ h,
                                                      const float* __restrict__ w2t,
                                                      const float* __restrict__ b2,
                                                      const float* __restrict__ sums,
                                                      const float* __restrict__ sumsq,
                                                      const float* __restrict__ gamma,
                                                      const float* __restrict__ beta,
                                                      float* __restrict__ out) {
  __shared__ float lds[64 * 134];
  __shared__ float s_scale[CH];
  __shared__ float s_shift[CH];
  const int t = threadIdx.x;
  const int b = blockIdx.x >> 7;
  const int n0 = (blockIdx.x & 127) << 6;
  if (t < CH) {
    const double cnt = (double)(BATCH * N_PTS);
    double mean = (double)sums[t] / cnt;
    double var = (double)sumsq[t] / cnt - mean * mean;
    double inv = 1.0 / sqrt(var + 1e-5);
    double sc = (double)gamma[t] * inv;
    s_scale[t] = (float)sc;
    s_shift[t] = (float)((double)beta[t] - mean * sc);
  }
  for (int idx = t; idx < CH * 64; idx += 1024) {
    int cc = idx >> 6, nl = idx & 63;
    lds[nl * 134 + cc] = h[((size_t)(b * CH + cc)) * N_PTS + n0 + nl];
  }
  __syncthreads();
  // apply BN + ReLU in LDS (same formula/values as fused_out's register path)
  for (int idx = t; idx < CH * 64; idx += 1024) {
    int cc = idx >> 6, nl = idx & 63;
    float v = lds[nl * 134 + cc];
    lds[nl * 134 + cc] = fmaxf(fmaf(v, s_scale[cc], s_shift[cc]), 0.0f);
  }
  __syncthreads();

  const int og = __builtin_amdgcn_readfirstlane(t >> 6);   // 0..15
  const int nl = t & 63;
  float acc2[8];
#pragma unroll
  for (int k = 0; k < 8; ++k) acc2[k] = b2[og * 8 + k];
  for (int c2 = 0; c2 < 64; ++c2) {
    float2 hv = *(const float2*)&lds[nl * 134 + 2 * c2];
    const float* wr0 = w2t + (2 * c2) * CH + og * 8;
    const float* wr1 = wr0 + CH;
#pragma unroll
    for (int k = 0; k < 8; ++k) acc2[k] = fmaf(wr0[k], hv.x, acc2[k]);
#pragma unroll
    for (int k = 0; k < 8; ++k) acc2[k] = fmaf(wr1[k], hv.y, acc2[k]);
  }
#pragma unroll
  for (int k = 0; k < 8; ++k) {
    int o = og * 8 + k;
    out[((size_t)(b * CH + o)) * N_PTS + n0 + nl] = acc2[k];
  }
}

// ======================================================================
// Kernel 5b (fallback, ws too small): original fused GEMM1+BN+ReLU+GEMM2
// ======================================================================
__global__ __launch_bounds__(256) void fused_out_kernel(const float* __restrict__ x,
                                                        const float4* __restrict__ nrm4,
                                                        const float* __restrict__ w1t,
                                                        const float* __restrict__ b1,
                                                        const float* __restrict__ w2t,
                                                        const float* __restrict__ b2,
                                                        const float* __restrict__ scale,
                                                        const float* __restrict__ shift,
                                                        float* __restrict__ out) {
  __shared__ float lds[64 * 134];
  const int t = threadIdx.x;
  const int b = blockIdx.x >> 7;
  const int n0 = (blockIdx.x & 127) << 6;
  for (int idx = t; idx < CH * 64; idx += 256) {
    int cc = idx >> 6, nl = idx & 63;
    lds[nl * 134 + cc] = x[((size_t)(b * CH + cc)) * N_PTS + n0 + nl];
  }
  if (t < 64) {
    float4 nv = nrm4[b * N_PTS + n0 + t];
    lds[t * 134 + 128] = nv.x; lds[t * 134 + 129] = nv.y;
    lds[t * 134 + 130] = nv.z; lds[t * 134 + 131] = 0.0f;
  }
  __syncthreads();

  const int og = __builtin_amdgcn_readfirstlane(t >> 6);
  const int nl = t & 63;
  float acc[32];
#pragma unroll
  for (int k = 0; k < 32; ++k) acc[k] = b1[og * 32 + k];
  for (int c2 = 0; c2 < 66; ++c2) {
    float2 xv = *(const float2*)&lds[nl * 134 + 2 * c2];
    const float* wr0 = w1t + (2 * c2) * CH + og * 32;
    const float* wr1 = wr0 + CH;
#pragma unroll
    for (int k = 0; k < 32; ++k) acc[k] = fmaf(wr0[k], xv.x, acc[k]);
#pragma unroll
    for (int k = 0; k < 32; ++k) acc[k] = fmaf(wr1[k], xv.y, acc[k]);
  }
#pragma unroll
  for (int k = 0; k < 32; ++k) {
    float sc = scale[og * 32 + k], sh = shift[og * 32 + k];
    acc[k] = fmaxf(fmaf(acc[k], sc, sh), 0.0f);
  }
  __syncthreads();
#pragma unroll
  for (int k2 = 0; k2 < 16; ++k2)
    *(float2*)&lds[nl * 134 + og * 32 + 2 * k2] = make_float2(acc[2 * k2], acc[2 * k2 + 1]);
  __syncthreads();

  float acc2[32];
#pragma unroll
  for (int k = 0; k < 32; ++k) acc2[k] = b2[og * 32 + k];
  for (int c2 = 0; c2 < 64; ++c2) {
    float2 hv = *(const float2*)&lds[nl * 134 + 2 * c2];
    const float* wr0 = w2t + (2 * c2) * CH + og * 32;
    const float* wr1 = wr0 + CH;
#pragma unroll
    for (int k = 0; k < 32; ++k) acc2[k] = fmaf(wr0[k], hv.x, acc2[k]);
#pragma unroll
    for (int k = 0; k < 32; ++k) acc2[k] = fmaf(wr1[k], hv.y, acc2[k]);
  }
#pragma unroll
  for (int k = 0; k < 32; ++k) {
    int o = og * 32 + k;
    out[((size_t)(b * CH + o)) * N_PTS + n0 + nl] = acc2[k];
  }
}

// ======================================================================
extern "C" void kernel_launch(void* const* d_in, const int* in_sizes, int n_in,
                              void* d_out, int out_size, void* d_ws, size_t ws_size,
                              hipStream_t stream) {
  const float* x     = (const float*)d_in[0];
  const float* xyz   = (const float*)d_in[1];
  const float* w1    = (const float*)d_in[2];
  const float* b1    = (const float*)d_in[3];
  const float* gamma = (const float*)d_in[4];
  const float* beta  = (const float*)d_in[5];
  const float* w2    = (const float*)d_in[6];
  const float* b2    = (const float*)d_in[7];
  float* out = (float*)d_out;

  float* W = (float*)d_ws;
  float4* xyz4 = (float4*)W;                         // floats [0, 131072)
  float4* nrm4 = (float4*)(W + 131072);              // floats [131072, 262144)
  float* w1t   = W + 262144;                         // [262144, 279040)
  float* w2t   = W + 279040;                         // [279040, 295424)
  float* stats = W + 295424;                         // [295424, 295680)
  float* scale = W + 295680;                         // [295680, 295808)
  float* shift = W + 295808;                         // [295808, 295936)
  unsigned short* nidx = (unsigned short*)(W + 295936);  // 32768*20 u16 = 327680 floats -> ends 623616
  float* h     = W + 624640;                         // 4*128*8192 floats = 16.78 MB (16B-aligned)

  const size_t need = (size_t)(624640 + (size_t)BATCH * CH * N_PTS) * 4;
  const bool use_h = (ws_size >= need);

  prep_kernel<<<128, 256, 0, stream>>>(xyz, w1, w2, xyz4, w1t, w2t, stats);
  knn_select_kernel<<<BATCH * N_PTS / 64, 1024, 0, stream>>>(xyz4, nidx);
  normals_kernel<<<BATCH * N_PTS / 64, 64, 0, stream>>>(xyz4, nidx, nrm4);
  gemm1_stats_kernel<<<BATCH * N_PTS / 64, 1024, 0, stream>>>(x, nrm4, w1t, b1, stats, stats + 128,
                                                              use_h ? h : nullptr);
  if (use_h) {
    bn_out_kernel<<<BATCH * N_PTS / 64, 1024, 0, stream>>>(h, w2t, b2, stats, stats + 128,
                                                           gamma, beta, out);
  } else {
    bn_finalize_kernel<<<1, 128, 0, stream>>>(stats, stats + 128, gamma, beta, scale, shift);
    fused_out_kernel<<<BATCH * N_PTS / 64, 256, 0, stream>>>(x, nrm4, w1t, b1, w2t, b2, scale, shift, out);
  }
}